// Round 10
// baseline (315.251 us; speedup 1.0000x reference)
//
#include <hip/hip_runtime.h>
#include <hip/hip_bf16.h>
#include <math.h>

#define BQ 100
#define SB 8
#define SS 4096
#define DD 256
#define HH 8
#define HDD 32
#define NSPLIT 4
#define SCHUNK (SS / NSPLIT)   // 1024
#define MROWS 800              // SB*BQ

typedef __attribute__((ext_vector_type(8))) short bf16x8;
typedef __attribute__((ext_vector_type(4))) float f32x4;

__device__ inline unsigned short f2bf(float f) {
    union { float f; unsigned u; } v; v.f = f;
    unsigned r = v.u + 0x7fff + ((v.u >> 16) & 1);
    return (unsigned short)(r >> 16);
}

__device__ inline bf16x8 load_bf8(const float* p) {
    float4 a = *(const float4*)p;
    float4 b = *(const float4*)(p + 4);
    bf16x8 r;
    r[0] = (short)f2bf(a.x); r[1] = (short)f2bf(a.y);
    r[2] = (short)f2bf(a.z); r[3] = (short)f2bf(a.w);
    r[4] = (short)f2bf(b.x); r[5] = (short)f2bf(b.y);
    r[6] = (short)f2bf(b.z); r[7] = (short)f2bf(b.w);
    return r;
}

#define TM 128
#define TN 128
#define TK 32
#define LSTR 40

// ============ stage1: fused {KV projection | maskpack | LN+Q-projection} ====
// grid.x: [0,1024) KV proj tiles; [1024,1824) maskpack rows; [1824,1874) LN+Qproj.
__global__ __launch_bounds__(256, 2) void stage1(
        const float* __restrict__ queries,
        const float* __restrict__ ln_g, const float* __restrict__ ln_b,
        const float* __restrict__ cw, const float* __restrict__ cb,
        float* __restrict__ q_cross,
        const float* __restrict__ pixel_feat,
        unsigned short* __restrict__ Kb, unsigned short* __restrict__ Vb,
        const float* __restrict__ mask, unsigned* __restrict__ Mbits) {
    __shared__ __align__(16) char smem[21504];
    const int bid = blockIdx.x;
    const int t = threadIdx.x;

    if (bid < 1024) {
        // ---- K+V projection: (32768x256)@(512x256)^T, head-blocked bf16 out
        typedef unsigned short (*tile_t)[LSTR];
        tile_t As = (tile_t)smem;
        tile_t Bs = (tile_t)(smem + 128 * LSTR * 2);
        const float* A = pixel_feat;
        const float* W = cw + (size_t)DD * DD;
        const float* bias = cb + DD;
        int m0 = (bid >> 2) * TM, n0 = (bid & 3) * TN;
        int wave = t / 64, lane = t % 64;
        int wm = (wave % 2) * 64, wn = (wave / 2) * 64;
        int lr = t / 4, lc = (t % 4) * 8;
        int fr = lane % 16, quad = lane / 16;
        f32x4 acc[4][4] = {};
        for (int k0 = 0; k0 < DD; k0 += TK) {
            __syncthreads();
#pragma unroll
            for (int half = 0; half < 2; half++) {
                int r = lr + half * 64;
                float4 a0 = *(const float4*)(A + (size_t)(m0 + r) * DD + k0 + lc);
                float4 a1 = *(const float4*)(A + (size_t)(m0 + r) * DD + k0 + lc + 4);
                uint4 pa;
                pa.x = (unsigned)f2bf(a0.x) | ((unsigned)f2bf(a0.y) << 16);
                pa.y = (unsigned)f2bf(a0.z) | ((unsigned)f2bf(a0.w) << 16);
                pa.z = (unsigned)f2bf(a1.x) | ((unsigned)f2bf(a1.y) << 16);
                pa.w = (unsigned)f2bf(a1.z) | ((unsigned)f2bf(a1.w) << 16);
                *(uint4*)&As[r][lc] = pa;
                float4 b0 = *(const float4*)(W + (size_t)(n0 + r) * DD + k0 + lc);
                float4 b1 = *(const float4*)(W + (size_t)(n0 + r) * DD + k0 + lc + 4);
                uint4 pb;
                pb.x = (unsigned)f2bf(b0.x) | ((unsigned)f2bf(b0.y) << 16);
                pb.y = (unsigned)f2bf(b0.z) | ((unsigned)f2bf(b0.w) << 16);
                pb.z = (unsigned)f2bf(b1.x) | ((unsigned)f2bf(b1.y) << 16);
                pb.w = (unsigned)f2bf(b1.z) | ((unsigned)f2bf(b1.w) << 16);
                *(uint4*)&Bs[r][lc] = pb;
            }
            __syncthreads();
            bf16x8 af[4], bf[4];
#pragma unroll
            for (int mi = 0; mi < 4; mi++)
                af[mi] = *(const bf16x8*)&As[wm + mi * 16 + fr][quad * 8];
#pragma unroll
            for (int ni = 0; ni < 4; ni++)
                bf[ni] = *(const bf16x8*)&Bs[wn + ni * 16 + fr][quad * 8];
#pragma unroll
            for (int mi = 0; mi < 4; mi++)
#pragma unroll
                for (int ni = 0; ni < 4; ni++)
                    acc[mi][ni] = __builtin_amdgcn_mfma_f32_16x16x32_bf16(
                        af[mi], bf[ni], acc[mi][ni], 0, 0, 0);
        }
#pragma unroll
        for (int ni = 0; ni < 4; ni++) {
            int n = n0 + wn + ni * 16 + fr;
            float bv = bias[n];
            unsigned short* dst = (n < 256) ? Kb : Vb;
            int hh = (n >> 5) & 7, d = n & 31;
#pragma unroll
            for (int mi = 0; mi < 4; mi++) {
#pragma unroll
                for (int r = 0; r < 4; r++) {
                    int m = m0 + wm + mi * 16 + quad * 4 + r;
                    int bb = m >> 12, s = m & (SS - 1);
                    dst[((((size_t)bb * HH + hh) * SS + s) << 5) + d] =
                        f2bf(acc[mi][ni][r] + bv);
                }
            }
        }
    } else if (bid < 1824) {
        // ---- mask pack row ----
        int row = bid - 1024;
        unsigned* words = (unsigned*)smem;
        unsigned* orred = (unsigned*)(smem + 512);
        int w = t >> 6, lane = t & 63;
        unsigned lor = 0;
        for (int i = 0; i < 16; i++) {
            int s = (w * 16 + i) * 64 + lane;
            unsigned long long bal = __ballot(mask[(size_t)row * SS + s] > 0.f);
            if (lane == 0) {
                words[(w * 16 + i) * 2] = (unsigned)bal;
                words[(w * 16 + i) * 2 + 1] = (unsigned)(bal >> 32);
            }
            lor |= (unsigned)(bal | (bal >> 32));
        }
        if (lane == 0) orred[w] = lor;
        __syncthreads();
        unsigned anyv = orred[0] | orred[1] | orred[2] | orred[3];
        if (t < 128) Mbits[(size_t)row * 128 + t] = anyv ? words[t] : 0xFFFFFFFFu;
    } else {
        // ---- LN(queries) + Q projection: 32 rows x 128 cols per block ----
        typedef unsigned short (*arow_t)[264];
        arow_t Aq = (arow_t)smem;                                  // 16896 B
        float* mu_s = (float*)(smem + 16896);                      // 32
        float* rs_s = mu_s + 32;                                   // 32
        float (*prt)[8][2] = (float(*)[8][2])(rs_s + 32);          // 2048 B
        int idx = bid - 1824;
        int nq = idx & 1, my = idx >> 1;
        int m0 = my * 32;
        int row = t & 31, cs = t >> 5;                              // 8 segs/row
        const float* xp = queries + (size_t)(m0 + row) * DD + cs * 32;
        float s = 0.f, ss = 0.f;
#pragma unroll
        for (int c = 0; c < 32; c += 4) {
            float4 v = *(const float4*)(xp + c);
            s += v.x + v.y + v.z + v.w;
            ss += v.x * v.x + v.y * v.y + v.z * v.z + v.w * v.w;
        }
        prt[row][cs][0] = s; prt[row][cs][1] = ss;
        __syncthreads();
        if (t < 32) {
            float sum = 0.f, sq = 0.f;
#pragma unroll
            for (int k = 0; k < 8; k++) { sum += prt[t][k][0]; sq += prt[t][k][1]; }
            float mu = sum * (1.0f / DD);
            float var = sq * (1.0f / DD) - mu * mu;
            mu_s[t] = mu;
            rs_s[t] = rsqrtf(var + 1e-5f);
        }
        __syncthreads();
        {
            float mu = mu_s[row], r = rs_s[row];
            int col0 = cs * 32;
#pragma unroll
            for (int c = 0; c < 32; c += 8) {
                int col = col0 + c;
                float4 v0 = *(const float4*)(xp + c);
                float4 v1 = *(const float4*)(xp + c + 4);
                float4 g0 = *(const float4*)(ln_g + col);
                float4 g1 = *(const float4*)(ln_g + col + 4);
                float4 b0 = *(const float4*)(ln_b + col);
                float4 b1 = *(const float4*)(ln_b + col + 4);
                uint4 pk;
                pk.x = (unsigned)f2bf((v0.x - mu) * r * g0.x + b0.x) |
                       ((unsigned)f2bf((v0.y - mu) * r * g0.y + b0.y) << 16);
                pk.y = (unsigned)f2bf((v0.z - mu) * r * g0.z + b0.z) |
                       ((unsigned)f2bf((v0.w - mu) * r * g0.w + b0.w) << 16);
                pk.z = (unsigned)f2bf((v1.x - mu) * r * g1.x + b1.x) |
                       ((unsigned)f2bf((v1.y - mu) * r * g1.y + b1.y) << 16);
                pk.w = (unsigned)f2bf((v1.z - mu) * r * g1.z + b1.z) |
                       ((unsigned)f2bf((v1.w - mu) * r * g1.w + b1.w) << 16);
                *(uint4*)&Aq[row][col] = pk;
            }
        }
        __syncthreads();
        int w = t >> 6, lane = t & 63;
        int fr = lane & 15, quad = lane >> 4;
        int n0 = nq * 128 + w * 32;
        f32x4 acc[2][2] = {};
        const float* Wp0 = cw + (size_t)(n0 + fr) * DD + quad * 8;
        const float* Wp1 = Wp0 + (size_t)16 * DD;
#pragma unroll
        for (int k0 = 0; k0 < DD; k0 += 32) {
            bf16x8 a0 = *(const bf16x8*)&Aq[fr][k0 + quad * 8];
            bf16x8 a1 = *(const bf16x8*)&Aq[16 + fr][k0 + quad * 8];
            bf16x8 w0 = load_bf8(Wp0 + k0);
            bf16x8 w1 = load_bf8(Wp1 + k0);
            acc[0][0] = __builtin_amdgcn_mfma_f32_16x16x32_bf16(a0, w0, acc[0][0], 0, 0, 0);
            acc[0][1] = __builtin_amdgcn_mfma_f32_16x16x32_bf16(a0, w1, acc[0][1], 0, 0, 0);
            acc[1][0] = __builtin_amdgcn_mfma_f32_16x16x32_bf16(a1, w0, acc[1][0], 0, 0, 0);
            acc[1][1] = __builtin_amdgcn_mfma_f32_16x16x32_bf16(a1, w1, acc[1][1], 0, 0, 0);
        }
#pragma unroll
        for (int ni = 0; ni < 2; ni++) {
            int n = n0 + ni * 16 + fr;
            float bv = cb[n];
#pragma unroll
            for (int mi = 0; mi < 2; mi++) {
#pragma unroll
                for (int r = 0; r < 4; r++) {
                    int m = m0 + mi * 16 + quad * 4 + r;
                    q_cross[(size_t)m * DD + n] = acc[mi][ni][r] + bv;
                }
            }
        }
    }
}

// ---------------- fused LayerNorm + one-wave MFMA GEMM ----------------------
template<int MODE>
__global__ __launch_bounds__(64, 4) void ln_gemm(
        const float* __restrict__ X, const float* __restrict__ gam,
        const float* __restrict__ bet,
        const float* __restrict__ W, const float* __restrict__ bias,
        const float* __restrict__ res,
        float* __restrict__ C, int N) {
    __shared__ unsigned short As[32][264];
    __shared__ float mu_s[32], rs_s[32];
    __shared__ float prt[32][2][2];
    const int t = threadIdx.x;
    const int fr = t & 15, quad = t >> 4;
    const int m0 = blockIdx.y * 32, n0 = blockIdx.x * 32;
    const int row = t & 31, half = t >> 5;

    const float* xp = X + (size_t)(m0 + row) * DD + half * 128;
    float s = 0.f, ss = 0.f;
#pragma unroll
    for (int c = 0; c < 128; c += 4) {
        float4 v = *(const float4*)(xp + c);
        s += v.x + v.y + v.z + v.w;
        ss += v.x * v.x + v.y * v.y + v.z * v.z + v.w * v.w;
    }
    prt[row][half][0] = s;
    prt[row][half][1] = ss;
    __syncthreads();
    if (t < 32) {
        float sum = prt[t][0][0] + prt[t][1][0];
        float sq  = prt[t][0][1] + prt[t][1][1];
        float mu = sum * (1.0f / DD);
        float var = sq * (1.0f / DD) - mu * mu;
        mu_s[t] = mu;
        rs_s[t] = rsqrtf(var + 1e-5f);
    }
    __syncthreads();
    {
        float mu = mu_s[row], r = rs_s[row];
#pragma unroll
        for (int c = 0; c < 128; c += 8) {
            int col = half * 128 + c;
            float4 v0 = *(const float4*)(xp + c);
            float4 v1 = *(const float4*)(xp + c + 4);
            float4 g0 = *(const float4*)(gam + col);
            float4 g1 = *(const float4*)(gam + col + 4);
            float4 b0 = *(const float4*)(bet + col);
            float4 b1 = *(const float4*)(bet + col + 4);
            uint4 pk;
            pk.x = (unsigned)f2bf((v0.x - mu) * r * g0.x + b0.x) |
                   ((unsigned)f2bf((v0.y - mu) * r * g0.y + b0.y) << 16);
            pk.y = (unsigned)f2bf((v0.z - mu) * r * g0.z + b0.z) |
                   ((unsigned)f2bf((v0.w - mu) * r * g0.w + b0.w) << 16);
            pk.z = (unsigned)f2bf((v1.x - mu) * r * g1.x + b1.x) |
                   ((unsigned)f2bf((v1.y - mu) * r * g1.y + b1.y) << 16);
            pk.w = (unsigned)f2bf((v1.z - mu) * r * g1.z + b1.z) |
                   ((unsigned)f2bf((v1.w - mu) * r * g1.w + b1.w) << 16);
            *(uint4*)&As[row][col] = pk;
        }
    }
    __syncthreads();

    f32x4 acc[2][2] = {};
    const float* Wp0 = W + (size_t)(n0 + fr) * DD + quad * 8;
    const float* Wp1 = Wp0 + (size_t)16 * DD;
#pragma unroll
    for (int k0 = 0; k0 < DD; k0 += 32) {
        bf16x8 a0 = *(const bf16x8*)&As[fr][k0 + quad * 8];
        bf16x8 a1 = *(const bf16x8*)&As[16 + fr][k0 + quad * 8];
        bf16x8 w0 = load_bf8(Wp0 + k0);
        bf16x8 w1 = load_bf8(Wp1 + k0);
        acc[0][0] = __builtin_amdgcn_mfma_f32_16x16x32_bf16(a0, w0, acc[0][0], 0, 0, 0);
        acc[0][1] = __builtin_amdgcn_mfma_f32_16x16x32_bf16(a0, w1, acc[0][1], 0, 0, 0);
        acc[1][0] = __builtin_amdgcn_mfma_f32_16x16x32_bf16(a1, w0, acc[1][0], 0, 0, 0);
        acc[1][1] = __builtin_amdgcn_mfma_f32_16x16x32_bf16(a1, w1, acc[1][1], 0, 0, 0);
    }

#pragma unroll
    for (int ni = 0; ni < 2; ni++) {
        int n = n0 + ni * 16 + fr;
        float bv = bias[n];
#pragma unroll
        for (int mi = 0; mi < 2; mi++) {
#pragma unroll
            for (int r = 0; r < 4; r++) {
                int m = m0 + mi * 16 + quad * 4 + r;
                float v = acc[mi][ni][r] + bv;
                if (MODE == 1) {
                    v = 0.5f * v * (1.0f + erff(v * 0.70710678118654752f));
                } else if (MODE == 2) {
                    v += res[(size_t)m * N + n];
                }
                C[(size_t)m * N + n] = v;
            }
        }
    }
}

// ---------------- fused split-S combine + output projection -----------------
__global__ __launch_bounds__(64, 4) void comb_gemm(
        const float* __restrict__ Opart, const float* __restrict__ mpart,
        const float* __restrict__ lpart,
        const float* __restrict__ W, const float* __restrict__ bias,
        const float* __restrict__ res,
        float* __restrict__ C) {
    __shared__ unsigned short As[32][264];
    const int t = threadIdx.x;
    const int fr = t & 15, quad = t >> 4;
    const int m0 = blockIdx.y * 32, n0 = blockIdx.x * 32;
    const int row = t & 31, half = t >> 5;

    {
        int m = m0 + row;
        int b = m / BQ, q = m % BQ;
#pragma unroll
        for (int h = half * 4; h < half * 4 + 4; h++) {
            float mv[NSPLIT], wsp[NSPLIT];
            float mstar = -1e30f;
#pragma unroll
            for (int sp = 0; sp < NSPLIT; sp++) {
                mv[sp] = mpart[((size_t)(b * NSPLIT + sp) * HH + h) * BQ + q];
                mstar = fmaxf(mstar, mv[sp]);
            }
            float lstar = 0.f;
#pragma unroll
            for (int sp = 0; sp < NSPLIT; sp++) {
                wsp[sp] = __expf(mv[sp] - mstar);
                lstar += lpart[((size_t)(b * NSPLIT + sp) * HH + h) * BQ + q] * wsp[sp];
            }
            float inv = 1.0f / lstar;
#pragma unroll
            for (int d = 0; d < HDD; d += 8) {
                float o[8] = {};
#pragma unroll
                for (int sp = 0; sp < NSPLIT; sp++) {
                    const float* op = Opart +
                        ((size_t)(b * NSPLIT + sp) * BQ + q) * DD + h * HDD + d;
                    float4 a = *(const float4*)op;
                    float4 b4 = *(const float4*)(op + 4);
                    o[0] += a.x * wsp[sp];  o[1] += a.y * wsp[sp];
                    o[2] += a.z * wsp[sp];  o[3] += a.w * wsp[sp];
                    o[4] += b4.x * wsp[sp]; o[5] += b4.y * wsp[sp];
                    o[6] += b4.z * wsp[sp]; o[7] += b4.w * wsp[sp];
                }
                uint4 pk;
                pk.x = (unsigned)f2bf(o[0] * inv) | ((unsigned)f2bf(o[1] * inv) << 16);
                pk.y = (unsigned)f2bf(o[2] * inv) | ((unsigned)f2bf(o[3] * inv) << 16);
                pk.z = (unsigned)f2bf(o[4] * inv) | ((unsigned)f2bf(o[5] * inv) << 16);
                pk.w = (unsigned)f2bf(o[6] * inv) | ((unsigned)f2bf(o[7] * inv) << 16);
                *(uint4*)&As[row][h * HDD + d] = pk;
            }
        }
    }
    __syncthreads();

    f32x4 acc[2][2] = {};
    const float* Wp0 = W + (size_t)(n0 + fr) * DD + quad * 8;
    const float* Wp1 = Wp0 + (size_t)16 * DD;
#pragma unroll
    for (int k0 = 0; k0 < DD; k0 += 32) {
        bf16x8 a0 = *(const bf16x8*)&As[fr][k0 + quad * 8];
        bf16x8 a1 = *(const bf16x8*)&As[16 + fr][k0 + quad * 8];
        bf16x8 w0 = load_bf8(Wp0 + k0);
        bf16x8 w1 = load_bf8(Wp1 + k0);
        acc[0][0] = __builtin_amdgcn_mfma_f32_16x16x32_bf16(a0, w0, acc[0][0], 0, 0, 0);
        acc[0][1] = __builtin_amdgcn_mfma_f32_16x16x32_bf16(a0, w1, acc[0][1], 0, 0, 0);
        acc[1][0] = __builtin_amdgcn_mfma_f32_16x16x32_bf16(a1, w0, acc[1][0], 0, 0, 0);
        acc[1][1] = __builtin_amdgcn_mfma_f32_16x16x32_bf16(a1, w1, acc[1][1], 0, 0, 0);
    }

#pragma unroll
    for (int ni = 0; ni < 2; ni++) {
        int n = n0 + ni * 16 + fr;
        float bv = bias[n];
#pragma unroll
        for (int mi = 0; mi < 2; mi++) {
#pragma unroll
            for (int r = 0; r < 4; r++) {
                int m = m0 + mi * 16 + quad * 4 + r;
                float v = acc[mi][ni][r] + bv + res[(size_t)m * DD + n];
                C[(size_t)m * DD + n] = v;
            }
        }
    }
}

// ---------------- one-wave MFMA GEMM (K=256, full epilogue) -----------------
template<int KK, int MODE>
__global__ __launch_bounds__(64, 4) void gemm_skinny2(
        const float* __restrict__ A, const float* __restrict__ W,
        const float* __restrict__ bias, const float* __restrict__ res,
        float* __restrict__ C, int N) {
    const int lane = threadIdx.x;
    const int fr = lane & 15, quad = lane >> 4;
    const int m0 = blockIdx.y * 32;
    const int n0 = blockIdx.x * 32;

    f32x4 acc[2][2] = {};
    const float* Ap0 = A + (size_t)(m0 + fr) * KK + quad * 8;
    const float* Ap1 = Ap0 + (size_t)16 * KK;
    const float* Wp0 = W + (size_t)(n0 + fr) * KK + quad * 8;
    const float* Wp1 = Wp0 + (size_t)16 * KK;

#pragma unroll
    for (int k0 = 0; k0 < KK; k0 += 32) {
        bf16x8 a0 = load_bf8(Ap0 + k0);
        bf16x8 a1 = load_bf8(Ap1 + k0);
        bf16x8 w0 = load_bf8(Wp0 + k0);
        bf16x8 w1 = load_bf8(Wp1 + k0);
        acc[0][0] = __builtin_amdgcn_mfma_f32_16x16x32_bf16(a0, w0, acc[0][0], 0, 0, 0);
        acc[0][1] = __builtin_amdgcn_mfma_f32_16x16x32_bf16(a0, w1, acc[0][1], 0, 0, 0);
        acc[1][0] = __builtin_amdgcn_mfma_f32_16x16x32_bf16(a1, w0, acc[1][0], 0, 0, 0);
        acc[1][1] = __builtin_amdgcn_mfma_f32_16x16x32_bf16(a1, w1, acc[1][1], 0, 0, 0);
    }

#pragma unroll
    for (int ni = 0; ni < 2; ni++) {
        int n = n0 + ni * 16 + fr;
        float bv = bias[n];
#pragma unroll
        for (int mi = 0; mi < 2; mi++) {
#pragma unroll
            for (int r = 0; r < 4; r++) {
                int m = m0 + mi * 16 + quad * 4 + r;
                float v = acc[mi][ni][r] + bv;
                if (MODE == 1) {
                    v = 0.5f * v * (1.0f + erff(v * 0.70710678118654752f));
                } else if (MODE == 2) {
                    v += res[(size_t)m * N + n];
                }
                C[(size_t)m * N + n] = v;
            }
        }
    }
}

// ---------------- FFN2: split-K=4 + last-block combine ----------------------
// grid (8, 25, 4); counters[25] must be zeroed before launch.
__global__ __launch_bounds__(64, 4) void gemm_ffn2(
        const float* __restrict__ A, const float* __restrict__ W,
        const float* __restrict__ bias, const float* __restrict__ res,
        float* __restrict__ C, float* __restrict__ Cp,
        unsigned* __restrict__ counters) {
    const int KK = 1024, KCH = 256, N = DD;
    __shared__ unsigned s_old;
    const int lane = threadIdx.x;
    const int fr = lane & 15, quad = lane >> 4;
    const int m0 = blockIdx.y * 32;
    const int n0 = blockIdx.x * 32;
    const int sk = blockIdx.z;

    f32x4 acc[2][2] = {};
    const float* Ap0 = A + (size_t)(m0 + fr) * KK + sk * KCH + quad * 8;
    const float* Ap1 = Ap0 + (size_t)16 * KK;
    const float* Wp0 = W + (size_t)(n0 + fr) * KK + sk * KCH + quad * 8;
    const float* Wp1 = Wp0 + (size_t)16 * KK;
#pragma unroll
    for (int k0 = 0; k0 < KCH; k0 += 32) {
        bf16x8 a0 = load_bf8(Ap0 + k0);
        bf16x8 a1 = load_bf8(Ap1 + k0);
        bf16x8 w0 = load_bf8(Wp0 + k0);
        bf16x8 w1 = load_bf8(Wp1 + k0);
        acc[0][0] = __builtin_amdgcn_mfma_f32_16x16x32_bf16(a0, w0, acc[0][0], 0, 0, 0);
        acc[0][1] = __builtin_amdgcn_mfma_f32_16x16x32_bf16(a0, w1, acc[0][1], 0, 0, 0);
        acc[1][0] = __builtin_amdgcn_mfma_f32_16x16x32_bf16(a1, w0, acc[1][0], 0, 0, 0);
        acc[1][1] = __builtin_amdgcn_mfma_f32_16x16x32_bf16(a1, w1, acc[1][1], 0, 0, 0);
    }
    float* dst = Cp + (size_t)sk * MROWS * N;
#pragma unroll
    for (int ni = 0; ni < 2; ni++) {
        int n = n0 + ni * 16 + fr;
#pragma unroll
        for (int mi = 0; mi < 2; mi++) {
#pragma unroll
            for (int r = 0; r < 4; r++) {
                int m = m0 + mi * 16 + quad * 4 + r;
                dst[(size_t)m * N + n] = acc[mi][ni][r];
            }
        }
    }
    __threadfence();
    if (lane == 0) s_old = atomicAdd(&counters[blockIdx.y], 1u);
    __syncthreads();
    if (s_old == 31) {              // last of 8 x-tiles * 4 sk for this row-tile
        __threadfence();
        // combine 32 rows x 256 cols, vectorized float4
        for (int v = lane; v < 32 * (DD / 4); v += 64) {
            int m = m0 + (v >> 6);
            int n4 = (v & 63) * 4;
            float4 b4 = *(const float4*)(bias + n4);
            float4 r4 = *(const float4*)(res + (size_t)m * DD + n4);
            float4 o = make_float4(b4.x + r4.x, b4.y + r4.y, b4.z + r4.z, b4.w + r4.w);
#pragma unroll
            for (int s = 0; s < 4; s++) {
                float4 p = *(const float4*)(Cp + ((size_t)s * MROWS + m) * DD + n4);
                o.x += p.x; o.y += p.y; o.z += p.z; o.w += p.w;
            }
            *(float4*)(C + (size_t)m * DD + n4) = o;
        }
    }
}

// ---------------- MFMA flash cross-attention, split-S, 64-q tiles -----------
#define QT 64
#define ST 128

__global__ __launch_bounds__(256) void cross_attn_mfma(
        const float* __restrict__ Qm,
        const unsigned short* __restrict__ Kb,
        const unsigned short* __restrict__ Vb,
        const unsigned* __restrict__ Mbits,
        float* __restrict__ Opart,
        float* __restrict__ mpart,
        float* __restrict__ lpart) {
    __shared__ unsigned short Qs[QT][40];
    __shared__ unsigned short Ks[ST][40];
    __shared__ unsigned short Vt[HDD][136];
    __shared__ unsigned short Ps[QT][136];
    __shared__ unsigned Mq[QT][4];
    __shared__ float red[QT][17];
    __shared__ float m_s[QT], alpha_s[QT], l_s[QT];

    const int qb = blockIdx.x, h = blockIdx.y;
    const int b = blockIdx.z / NSPLIT, sp = blockIdx.z % NSPLIT;
    const int t = threadIdx.x;
    const int w = t >> 6, lane = t & 63;
    const int fr = lane & 15, quad = lane >> 4;
    const int q0 = qb * QT;
    const int qlim = min(BQ - q0, QT);

    {
        int q = t >> 2, c0 = (t & 3) * 8;
        float4 v0 = make_float4(0.f, 0.f, 0.f, 0.f), v1 = v0;
        if (q < qlim) {
            const float* qp = Qm + (size_t)(b * BQ + q0 + q) * DD + h * HDD + c0;
            v0 = *(const float4*)qp;
            v1 = *(const float4*)(qp + 4);
        }
        const float sc = 0.17677669529663687f;
        uint4 pq;
        pq.x = (unsigned)f2bf(v0.x * sc) | ((unsigned)f2bf(v0.y * sc) << 16);
        pq.y = (unsigned)f2bf(v0.z * sc) | ((unsigned)f2bf(v0.w * sc) << 16);
        pq.z = (unsigned)f2bf(v1.x * sc) | ((unsigned)f2bf(v1.y * sc) << 16);
        pq.w = (unsigned)f2bf(v1.z * sc) | ((unsigned)f2bf(v1.w * sc) << 16);
        *(uint4*)&Qs[q][c0] = pq;
        if (t < QT) { m_s[t] = -1e30f; l_s[t] = 0.f; }
    }

    f32x4 oacc[2] = {};
    const unsigned short* Kbase = Kb + (((size_t)(b * HH + h)) * SS << 5);
    const unsigned short* Vbase = Vb + (((size_t)(b * HH + h)) * SS << 5);

    for (int s0 = sp * SCHUNK; s0 < (sp + 1) * SCHUNK; s0 += ST) {
        __syncthreads();
        {
            int r = t >> 1, half = t & 1;
            const unsigned short* kp = Kbase + ((size_t)(s0 + r) << 5) + half * 16;
            *(uint4*)&Ks[r][half * 16] = *(const uint4*)kp;
            *(uint4*)&Ks[r][half * 16 + 8] = *(const uint4*)(kp + 8);
            const unsigned short* vp = Vbase + ((size_t)(s0 + r) << 5) + half * 16;
            union { uint4 u; unsigned short s[8]; } v0, v1;
            v0.u = *(const uint4*)vp;
            v1.u = *(const uint4*)(vp + 8);
#pragma unroll
            for (int j = 0; j < 8; j++) Vt[half * 16 + j][r] = v0.s[j];
#pragma unroll
            for (int j = 0; j < 8; j++) Vt[half * 16 + 8 + j][r] = v1.s[j];
        }
        {
            int q = t >> 2, wd = t & 3;
            unsigned mword = 0xFFFFFFFFu;
            if (q < qlim)
                mword = Mbits[(size_t)(b * BQ + q0 + q) * 128 + (s0 >> 5) + wd];
            Mq[q][wd] = mword;
        }
        __syncthreads();

        bf16x8 af[2];
#pragma unroll
        for (int mt = 0; mt < 2; mt++)
            af[mt] = *(const bf16x8*)&Ks[w * 32 + mt * 16 + fr][quad * 8];
        f32x4 st[2][4];
#pragma unroll
        for (int nt = 0; nt < 4; nt++) {
            bf16x8 bq = *(const bf16x8*)&Qs[nt * 16 + fr][quad * 8];
#pragma unroll
            for (int mt = 0; mt < 2; mt++) {
                f32x4 z = {0.f, 0.f, 0.f, 0.f};
                st[mt][nt] = __builtin_amdgcn_mfma_f32_16x16x32_bf16(af[mt], bq, z, 0, 0, 0);
            }
        }

        float pmax[4] = {-1e30f, -1e30f, -1e30f, -1e30f};
#pragma unroll
        for (int nt = 0; nt < 4; nt++) {
            unsigned mword = Mq[nt * 16 + fr][w];
#pragma unroll
            for (int mt = 0; mt < 2; mt++)
#pragma unroll
                for (int r = 0; r < 4; r++) {
                    int bitpos = mt * 16 + quad * 4 + r;
                    float v = st[mt][nt][r];
                    if (!((mword >> bitpos) & 1u)) v -= 10000.f;
                    st[mt][nt][r] = v;
                    pmax[nt] = fmaxf(pmax[nt], v);
                }
        }
#pragma unroll
        for (int nt = 0; nt < 4; nt++)
            red[nt * 16 + fr][w * 4 + quad] = pmax[nt];
        __syncthreads();

        if (t < QT) {
            float mt_ = -1e30f;
#pragma unroll
            for (int k = 0; k < 16; k++) mt_ = fmaxf(mt_, red[t][k]);
            float mo = m_s[t], mn = fmaxf(mo, mt_);
            m_s[t] = mn;
            alpha_s[t] = __expf(mo - mn);
        }
        __syncthreads();

        float psum[4] = {0.f, 0.f, 0.f, 0.f};
#pragma unroll
        for (int nt = 0; nt < 4; nt++) {
            float mrow = m_s[nt * 16 + fr];
#pragma unroll
            for (int mt = 0; mt < 2; mt++) {
                float p0 = __expf(st[mt][nt][0] - mrow);
                float p1 = __expf(st[mt][nt][1] - mrow);
                float p2 = __expf(st[mt][nt][2] - mrow);
                float p3 = __expf(st[mt][nt][3] - mrow);
                psum[nt] += p0 + p1 + p2 + p3;
                ushort4 pk;
                pk.x = f2bf(p0); pk.y = f2bf(p1); pk.z = f2bf(p2); pk.w = f2bf(p3);
                *(ushort4*)&Ps[nt * 16 + fr][w * 32 + mt * 16 + quad * 4] = pk;
            }
        }
#pragma unroll
        for (int nt = 0; nt < 4; nt++)
            red[nt * 16 + fr][w * 4 + quad] = psum[nt];
        __syncthreads();

        if (t < QT) {
            float s = 0.f;
#pragma unroll
            for (int k = 0; k < 16; k++) s += red[t][k];
            l_s[t] = l_s[t] * alpha_s[t] + s;
        }

#pragma unroll
        for (int r = 0; r < 4; r++) {
            float a = alpha_s[w * 16 + quad * 4 + r];
            oacc[0][r] *= a; oacc[1][r] *= a;
        }
#pragma unroll
        for (int k0 = 0; k0 < ST; k0 += 32) {
            bf16x8 ap = *(const bf16x8*)&Ps[w * 16 + fr][k0 + quad * 8];
            bf16x8 bv0 = *(const bf16x8*)&Vt[fr][k0 + quad * 8];
            bf16x8 bv1 = *(const bf16x8*)&Vt[16 + fr][k0 + quad * 8];
            oacc[0] = __builtin_amdgcn_mfma_f32_16x16x32_bf16(ap, bv0, oacc[0], 0, 0, 0);
            oacc[1] = __builtin_amdgcn_mfma_f32_16x16x32_bf16(ap, bv1, oacc[1], 0, 0, 0);
        }
    }
    __syncthreads();

    int part = b * NSPLIT + sp;
    if (t < qlim) {
        mpart[((size_t)part * HH + h) * BQ + q0 + t] = m_s[t];
        lpart[((size_t)part * HH + h) * BQ + q0 + t] = l_s[t];
    }
#pragma unroll
    for (int nd = 0; nd < 2; nd++) {
#pragma unroll
        for (int r = 0; r < 4; r++) {
            int q = w * 16 + quad * 4 + r;
            if (q < qlim)
                Opart[((size_t)part * BQ + q0 + q) * DD + h * HDD + nd * 16 + fr] = oacc[nd][r];
        }
    }
}

// ---------------- self-attention (S=Q=100) ----------------------------------
__global__ void attn_kernel(const float* __restrict__ Qm, int sq, int qo0,
                            const float* __restrict__ Km, int sk, int ko0,
                            const float* __restrict__ Vm, int sv, int vo0,
                            float* __restrict__ Out, int so, int oo0,
                            int Slen, int Qlen, float scale) {
    int q = blockIdx.x, h = blockIdx.y, b = blockIdx.z;
    int tid = threadIdx.x;
    __shared__ float qv[32];
    __shared__ float sc[128];
    __shared__ float red[256];
    __shared__ float part[8][33];
    int qrow = b * Qlen + q;
    if (tid < 32) qv[tid] = Qm[(size_t)qrow * sq + qo0 + h * HDD + tid] * scale;
    __syncthreads();

    float lmax = -1e30f;
    for (int s = tid; s < Slen; s += 256) {
        const float* kp = Km + (size_t)(b * Slen + s) * sk + ko0 + h * HDD;
        float dot = 0.f;
#pragma unroll
        for (int d = 0; d < HDD; d += 4) {
            float4 k4 = *(const float4*)(kp + d);
            dot += qv[d] * k4.x + qv[d + 1] * k4.y + qv[d + 2] * k4.z + qv[d + 3] * k4.w;
        }
        sc[s] = dot;
        lmax = fmaxf(lmax, dot);
    }
    red[tid] = lmax; __syncthreads();
    for (int off = 128; off > 0; off >>= 1) {
        if (tid < off) red[tid] = fmaxf(red[tid], red[tid + off]);
        __syncthreads();
    }
    float m = red[0];
    __syncthreads();
    float lsum = 0.f;
    for (int s = tid; s < Slen; s += 256) {
        float e = __expf(sc[s] - m);
        sc[s] = e;
        lsum += e;
    }
    red[tid] = lsum; __syncthreads();
    for (int off = 128; off > 0; off >>= 1) {
        if (tid < off) red[tid] += red[tid + off];
        __syncthreads();
    }
    float inv = 1.0f / red[0];

    int d = tid & 31, g = tid >> 5;
    float acc = 0.f;
    for (int s = g; s < Slen; s += 8)
        acc += sc[s] * Vm[(size_t)(b * Slen + s) * sv + vo0 + h * HDD + d];
    part[g][d] = acc; __syncthreads();
    if (g == 0) {
        float t = 0.f;
#pragma unroll
        for (int gg = 0; gg < 8; gg++) t += part[gg][d];
        Out[(size_t)qrow * so + oo0 + h * HDD + d] = t * inv;
    }
}

extern "C" void kernel_launch(void* const* d_in, const int* in_sizes, int n_in,
                              void* d_out, int out_size, void* d_ws, size_t ws_size,
                              hipStream_t stream) {
    const float* queries    = (const float*)d_in[0];
    const float* pixel_feat = (const float*)d_in[1];
    const float* prev_mask  = (const float*)d_in[2];
    const float* cross_in_w  = (const float*)d_in[3];
    const float* cross_in_b  = (const float*)d_in[4];
    const float* cross_out_w = (const float*)d_in[5];
    const float* cross_out_b = (const float*)d_in[6];
    const float* self_in_w   = (const float*)d_in[7];
    const float* self_in_b   = (const float*)d_in[8];
    const float* self_out_w  = (const float*)d_in[9];
    const float* self_out_b  = (const float*)d_in[10];
    const float* ln_cross_g  = (const float*)d_in[11];
    const float* ln_cross_b  = (const float*)d_in[12];
    const float* ln_self_g   = (const float*)d_in[13];
    const float* ln_self_b   = (const float*)d_in[14];
    const float* ln_ffn_g    = (const float*)d_in[15];
    const float* ln_ffn_b    = (const float*)d_in[16];
    const float* ffn_w1 = (const float*)d_in[17];
    const float* ffn_b1 = (const float*)d_in[18];
    const float* ffn_w2 = (const float*)d_in[19];
    const float* ffn_b2 = (const float*)d_in[20];
    float* out = (float*)d_out;

    const int NQ = SB * BQ;        // 800
    const int NK = SB * SS;        // 32768

    float* ws = (float*)d_ws;
    unsigned* counters = (unsigned*)ws; ws += 32;
    unsigned* Mbits = (unsigned*)ws;   ws += (size_t)NQ * 128;
    float* q_cross  = ws;              ws += (size_t)NQ * DD;
    unsigned short* Kbk = (unsigned short*)ws;
    ws += (size_t)NK * DD / 2;
    unsigned short* Vbk = (unsigned short*)ws;
    ws += (size_t)NK * DD / 2;
    float* queries1 = ws;              ws += (size_t)NQ * DD;
    float* qkv      = ws;              ws += (size_t)NQ * 3 * DD;
    float* attn2    = ws;              ws += (size_t)NQ * DD;
    float* queries2 = ws;              ws += (size_t)NQ * DD;
    float* ffn_h    = ws;              ws += (size_t)NQ * 4 * DD;
    float* Csplit   = ws;              ws += (size_t)4 * MROWS * DD;
    float* Opart    = ws;              ws += (size_t)SB * NSPLIT * BQ * DD;
    float* mpart    = ws;              ws += (size_t)SB * NSPLIT * HH * BQ;
    float* lpart    = ws;              ws += (size_t)SB * NSPLIT * HH * BQ;

    const float scale = 0.17677669529663687f;

    hipMemsetAsync(counters, 0, 32 * sizeof(unsigned), stream);

    // ---- stage1: KV proj + maskpack + LN/Q-proj (one dispatch) ----
    stage1<<<1874, 256, 0, stream>>>(
        queries, ln_cross_g, ln_cross_b, cross_in_w, cross_in_b, q_cross,
        pixel_feat, Kbk, Vbk, prev_mask, Mbits);

    // ---- cross attention ----
    cross_attn_mfma<<<dim3(2, HH, SB * NSPLIT), 256, 0, stream>>>(
        q_cross, Kbk, Vbk, Mbits, Opart, mpart, lpart);
    comb_gemm<<<dim3(8, 25), 64, 0, stream>>>(
        Opart, mpart, lpart, cross_out_w, cross_out_b, queries, queries1);

    // ---- self attention ----
    ln_gemm<0><<<dim3(24, 25), 64, 0, stream>>>(
        queries1, ln_self_g, ln_self_b, self_in_w, self_in_b, nullptr,
        qkv, 3 * DD);
    attn_kernel<<<dim3(BQ, HH, SB), 256, 0, stream>>>(
        qkv, 3 * DD, 0, qkv, 3 * DD, DD, qkv, 3 * DD, 2 * DD,
        attn2, DD, 0, BQ, BQ, scale);
    gemm_skinny2<256, 2><<<dim3(8, 25), 64, 0, stream>>>(
        attn2, self_out_w, self_out_b, queries1, queries2, DD);

    // ---- FFN ----
    ln_gemm<1><<<dim3(32, 25), 64, 0, stream>>>(
        queries2, ln_ffn_g, ln_ffn_b, ffn_w1, ffn_b1, nullptr,
        ffn_h, 4 * DD);
    gemm_ffn2<<<dim3(8, 25, 4), 64, 0, stream>>>(
        ffn_h, ffn_w2, ffn_b2, queries2, out, Csplit, counters);
}

// Round 11
// 272.672 us; speedup vs baseline: 1.1562x; 1.1562x over previous
//
#include <hip/hip_runtime.h>
#include <hip/hip_bf16.h>
#include <math.h>

#define BQ 100
#define SB 8
#define SS 4096
#define DD 256
#define HH 8
#define HDD 32
#define NSPLIT 4
#define SCHUNK (SS / NSPLIT)   // 1024
#define MROWS 800              // SB*BQ

typedef __attribute__((ext_vector_type(8))) short bf16x8;
typedef __attribute__((ext_vector_type(4))) float f32x4;

__device__ inline unsigned short f2bf(float f) {
    union { float f; unsigned u; } v; v.f = f;
    unsigned r = v.u + 0x7fff + ((v.u >> 16) & 1);
    return (unsigned short)(r >> 16);
}

__device__ inline bf16x8 load_bf8(const float* p) {
    float4 a = *(const float4*)p;
    float4 b = *(const float4*)(p + 4);
    bf16x8 r;
    r[0] = (short)f2bf(a.x); r[1] = (short)f2bf(a.y);
    r[2] = (short)f2bf(a.z); r[3] = (short)f2bf(a.w);
    r[4] = (short)f2bf(b.x); r[5] = (short)f2bf(b.y);
    r[6] = (short)f2bf(b.z); r[7] = (short)f2bf(b.w);
    return r;
}

#define TM 128
#define TN 128
#define TK 32
#define LSTR 40

// ============ stage1: fused {KV projection | maskpack | LN+Q-projection} ====
// grid.x: [0,1024) KV proj tiles; [1024,1824) maskpack rows; [1824,1874) LN+Qproj.
__global__ __launch_bounds__(256, 2) void stage1(
        const float* __restrict__ queries,
        const float* __restrict__ ln_g, const float* __restrict__ ln_b,
        const float* __restrict__ cw, const float* __restrict__ cb,
        float* __restrict__ q_cross,
        const float* __restrict__ pixel_feat,
        unsigned short* __restrict__ Kb, unsigned short* __restrict__ Vb,
        const float* __restrict__ mask, unsigned* __restrict__ Mbits) {
    __shared__ __align__(16) char smem[21504];
    const int bid = blockIdx.x;
    const int t = threadIdx.x;

    if (bid < 1024) {
        typedef unsigned short (*tile_t)[LSTR];
        tile_t As = (tile_t)smem;
        tile_t Bs = (tile_t)(smem + 128 * LSTR * 2);
        const float* A = pixel_feat;
        const float* W = cw + (size_t)DD * DD;
        const float* bias = cb + DD;
        int m0 = (bid >> 2) * TM, n0 = (bid & 3) * TN;
        int wave = t / 64, lane = t % 64;
        int wm = (wave % 2) * 64, wn = (wave / 2) * 64;
        int lr = t / 4, lc = (t % 4) * 8;
        int fr = lane % 16, quad = lane / 16;
        f32x4 acc[4][4] = {};
        for (int k0 = 0; k0 < DD; k0 += TK) {
            __syncthreads();
#pragma unroll
            for (int half = 0; half < 2; half++) {
                int r = lr + half * 64;
                float4 a0 = *(const float4*)(A + (size_t)(m0 + r) * DD + k0 + lc);
                float4 a1 = *(const float4*)(A + (size_t)(m0 + r) * DD + k0 + lc + 4);
                uint4 pa;
                pa.x = (unsigned)f2bf(a0.x) | ((unsigned)f2bf(a0.y) << 16);
                pa.y = (unsigned)f2bf(a0.z) | ((unsigned)f2bf(a0.w) << 16);
                pa.z = (unsigned)f2bf(a1.x) | ((unsigned)f2bf(a1.y) << 16);
                pa.w = (unsigned)f2bf(a1.z) | ((unsigned)f2bf(a1.w) << 16);
                *(uint4*)&As[r][lc] = pa;
                float4 b0 = *(const float4*)(W + (size_t)(n0 + r) * DD + k0 + lc);
                float4 b1 = *(const float4*)(W + (size_t)(n0 + r) * DD + k0 + lc + 4);
                uint4 pb;
                pb.x = (unsigned)f2bf(b0.x) | ((unsigned)f2bf(b0.y) << 16);
                pb.y = (unsigned)f2bf(b0.z) | ((unsigned)f2bf(b0.w) << 16);
                pb.z = (unsigned)f2bf(b1.x) | ((unsigned)f2bf(b1.y) << 16);
                pb.w = (unsigned)f2bf(b1.z) | ((unsigned)f2bf(b1.w) << 16);
                *(uint4*)&Bs[r][lc] = pb;
            }
            __syncthreads();
            bf16x8 af[4], bf[4];
#pragma unroll
            for (int mi = 0; mi < 4; mi++)
                af[mi] = *(const bf16x8*)&As[wm + mi * 16 + fr][quad * 8];
#pragma unroll
            for (int ni = 0; ni < 4; ni++)
                bf[ni] = *(const bf16x8*)&Bs[wn + ni * 16 + fr][quad * 8];
#pragma unroll
            for (int mi = 0; mi < 4; mi++)
#pragma unroll
                for (int ni = 0; ni < 4; ni++)
                    acc[mi][ni] = __builtin_amdgcn_mfma_f32_16x16x32_bf16(
                        af[mi], bf[ni], acc[mi][ni], 0, 0, 0);
        }
#pragma unroll
        for (int ni = 0; ni < 4; ni++) {
            int n = n0 + wn + ni * 16 + fr;
            float bv = bias[n];
            unsigned short* dst = (n < 256) ? Kb : Vb;
            int hh = (n >> 5) & 7, d = n & 31;
#pragma unroll
            for (int mi = 0; mi < 4; mi++) {
#pragma unroll
                for (int r = 0; r < 4; r++) {
                    int m = m0 + wm + mi * 16 + quad * 4 + r;
                    int bb = m >> 12, s = m & (SS - 1);
                    dst[((((size_t)bb * HH + hh) * SS + s) << 5) + d] =
                        f2bf(acc[mi][ni][r] + bv);
                }
            }
        }
    } else if (bid < 1824) {
        int row = bid - 1024;
        unsigned* words = (unsigned*)smem;
        unsigned* orred = (unsigned*)(smem + 512);
        int w = t >> 6, lane = t & 63;
        unsigned lor = 0;
        for (int i = 0; i < 16; i++) {
            int s = (w * 16 + i) * 64 + lane;
            unsigned long long bal = __ballot(mask[(size_t)row * SS + s] > 0.f);
            if (lane == 0) {
                words[(w * 16 + i) * 2] = (unsigned)bal;
                words[(w * 16 + i) * 2 + 1] = (unsigned)(bal >> 32);
            }
            lor |= (unsigned)(bal | (bal >> 32));
        }
        if (lane == 0) orred[w] = lor;
        __syncthreads();
        unsigned anyv = orred[0] | orred[1] | orred[2] | orred[3];
        if (t < 128) Mbits[(size_t)row * 128 + t] = anyv ? words[t] : 0xFFFFFFFFu;
    } else {
        typedef unsigned short (*arow_t)[264];
        arow_t Aq = (arow_t)smem;
        float* mu_s = (float*)(smem + 16896);
        float* rs_s = mu_s + 32;
        float (*prt)[8][2] = (float(*)[8][2])(rs_s + 32);
        int idx = bid - 1824;
        int nq = idx & 1, my = idx >> 1;
        int m0 = my * 32;
        int row = t & 31, cs = t >> 5;
        const float* xp = queries + (size_t)(m0 + row) * DD + cs * 32;
        float s = 0.f, ss = 0.f;
#pragma unroll
        for (int c = 0; c < 32; c += 4) {
            float4 v = *(const float4*)(xp + c);
            s += v.x + v.y + v.z + v.w;
            ss += v.x * v.x + v.y * v.y + v.z * v.z + v.w * v.w;
        }
        prt[row][cs][0] = s; prt[row][cs][1] = ss;
        __syncthreads();
        if (t < 32) {
            float sum = 0.f, sq = 0.f;
#pragma unroll
            for (int k = 0; k < 8; k++) { sum += prt[t][k][0]; sq += prt[t][k][1]; }
            float mu = sum * (1.0f / DD);
            float var = sq * (1.0f / DD) - mu * mu;
            mu_s[t] = mu;
            rs_s[t] = rsqrtf(var + 1e-5f);
        }
        __syncthreads();
        {
            float mu = mu_s[row], r = rs_s[row];
            int col0 = cs * 32;
#pragma unroll
            for (int c = 0; c < 32; c += 8) {
                int col = col0 + c;
                float4 v0 = *(const float4*)(xp + c);
                float4 v1 = *(const float4*)(xp + c + 4);
                float4 g0 = *(const float4*)(ln_g + col);
                float4 g1 = *(const float4*)(ln_g + col + 4);
                float4 b0 = *(const float4*)(ln_b + col);
                float4 b1 = *(const float4*)(ln_b + col + 4);
                uint4 pk;
                pk.x = (unsigned)f2bf((v0.x - mu) * r * g0.x + b0.x) |
                       ((unsigned)f2bf((v0.y - mu) * r * g0.y + b0.y) << 16);
                pk.y = (unsigned)f2bf((v0.z - mu) * r * g0.z + b0.z) |
                       ((unsigned)f2bf((v0.w - mu) * r * g0.w + b0.w) << 16);
                pk.z = (unsigned)f2bf((v1.x - mu) * r * g1.x + b1.x) |
                       ((unsigned)f2bf((v1.y - mu) * r * g1.y + b1.y) << 16);
                pk.w = (unsigned)f2bf((v1.z - mu) * r * g1.z + b1.z) |
                       ((unsigned)f2bf((v1.w - mu) * r * g1.w + b1.w) << 16);
                *(uint4*)&Aq[row][col] = pk;
            }
        }
        __syncthreads();
        int w = t >> 6, lane = t & 63;
        int fr = lane & 15, quad = lane >> 4;
        int n0 = nq * 128 + w * 32;
        f32x4 acc[2][2] = {};
        const float* Wp0 = cw + (size_t)(n0 + fr) * DD + quad * 8;
        const float* Wp1 = Wp0 + (size_t)16 * DD;
#pragma unroll
        for (int k0 = 0; k0 < DD; k0 += 32) {
            bf16x8 a0 = *(const bf16x8*)&Aq[fr][k0 + quad * 8];
            bf16x8 a1 = *(const bf16x8*)&Aq[16 + fr][k0 + quad * 8];
            bf16x8 w0 = load_bf8(Wp0 + k0);
            bf16x8 w1 = load_bf8(Wp1 + k0);
            acc[0][0] = __builtin_amdgcn_mfma_f32_16x16x32_bf16(a0, w0, acc[0][0], 0, 0, 0);
            acc[0][1] = __builtin_amdgcn_mfma_f32_16x16x32_bf16(a0, w1, acc[0][1], 0, 0, 0);
            acc[1][0] = __builtin_amdgcn_mfma_f32_16x16x32_bf16(a1, w0, acc[1][0], 0, 0, 0);
            acc[1][1] = __builtin_amdgcn_mfma_f32_16x16x32_bf16(a1, w1, acc[1][1], 0, 0, 0);
        }
#pragma unroll
        for (int ni = 0; ni < 2; ni++) {
            int n = n0 + ni * 16 + fr;
            float bv = cb[n];
#pragma unroll
            for (int mi = 0; mi < 2; mi++) {
#pragma unroll
                for (int r = 0; r < 4; r++) {
                    int m = m0 + mi * 16 + quad * 4 + r;
                    q_cross[(size_t)m * DD + n] = acc[mi][ni][r] + bv;
                }
            }
        }
    }
}

// ---------------- fused LayerNorm + one-wave MFMA GEMM ----------------------
template<int MODE>
__global__ __launch_bounds__(64, 4) void ln_gemm(
        const float* __restrict__ X, const float* __restrict__ gam,
        const float* __restrict__ bet,
        const float* __restrict__ W, const float* __restrict__ bias,
        const float* __restrict__ res,
        float* __restrict__ C, int N) {
    __shared__ unsigned short As[32][264];
    __shared__ float mu_s[32], rs_s[32];
    __shared__ float prt[32][2][2];
    const int t = threadIdx.x;
    const int fr = t & 15, quad = t >> 4;
    const int m0 = blockIdx.y * 32, n0 = blockIdx.x * 32;
    const int row = t & 31, half = t >> 5;

    const float* xp = X + (size_t)(m0 + row) * DD + half * 128;
    float s = 0.f, ss = 0.f;
#pragma unroll
    for (int c = 0; c < 128; c += 4) {
        float4 v = *(const float4*)(xp + c);
        s += v.x + v.y + v.z + v.w;
        ss += v.x * v.x + v.y * v.y + v.z * v.z + v.w * v.w;
    }
    prt[row][half][0] = s;
    prt[row][half][1] = ss;
    __syncthreads();
    if (t < 32) {
        float sum = prt[t][0][0] + prt[t][1][0];
        float sq  = prt[t][0][1] + prt[t][1][1];
        float mu = sum * (1.0f / DD);
        float var = sq * (1.0f / DD) - mu * mu;
        mu_s[t] = mu;
        rs_s[t] = rsqrtf(var + 1e-5f);
    }
    __syncthreads();
    {
        float mu = mu_s[row], r = rs_s[row];
#pragma unroll
        for (int c = 0; c < 128; c += 8) {
            int col = half * 128 + c;
            float4 v0 = *(const float4*)(xp + c);
            float4 v1 = *(const float4*)(xp + c + 4);
            float4 g0 = *(const float4*)(gam + col);
            float4 g1 = *(const float4*)(gam + col + 4);
            float4 b0 = *(const float4*)(bet + col);
            float4 b1 = *(const float4*)(bet + col + 4);
            uint4 pk;
            pk.x = (unsigned)f2bf((v0.x - mu) * r * g0.x + b0.x) |
                   ((unsigned)f2bf((v0.y - mu) * r * g0.y + b0.y) << 16);
            pk.y = (unsigned)f2bf((v0.z - mu) * r * g0.z + b0.z) |
                   ((unsigned)f2bf((v0.w - mu) * r * g0.w + b0.w) << 16);
            pk.z = (unsigned)f2bf((v1.x - mu) * r * g1.x + b1.x) |
                   ((unsigned)f2bf((v1.y - mu) * r * g1.y + b1.y) << 16);
            pk.w = (unsigned)f2bf((v1.z - mu) * r * g1.z + b1.z) |
                   ((unsigned)f2bf((v1.w - mu) * r * g1.w + b1.w) << 16);
            *(uint4*)&As[row][col] = pk;
        }
    }
    __syncthreads();

    f32x4 acc[2][2] = {};
    const float* Wp0 = W + (size_t)(n0 + fr) * DD + quad * 8;
    const float* Wp1 = Wp0 + (size_t)16 * DD;
#pragma unroll
    for (int k0 = 0; k0 < DD; k0 += 32) {
        bf16x8 a0 = *(const bf16x8*)&As[fr][k0 + quad * 8];
        bf16x8 a1 = *(const bf16x8*)&As[16 + fr][k0 + quad * 8];
        bf16x8 w0 = load_bf8(Wp0 + k0);
        bf16x8 w1 = load_bf8(Wp1 + k0);
        acc[0][0] = __builtin_amdgcn_mfma_f32_16x16x32_bf16(a0, w0, acc[0][0], 0, 0, 0);
        acc[0][1] = __builtin_amdgcn_mfma_f32_16x16x32_bf16(a0, w1, acc[0][1], 0, 0, 0);
        acc[1][0] = __builtin_amdgcn_mfma_f32_16x16x32_bf16(a1, w0, acc[1][0], 0, 0, 0);
        acc[1][1] = __builtin_amdgcn_mfma_f32_16x16x32_bf16(a1, w1, acc[1][1], 0, 0, 0);
    }

#pragma unroll
    for (int ni = 0; ni < 2; ni++) {
        int n = n0 + ni * 16 + fr;
        float bv = bias[n];
#pragma unroll
        for (int mi = 0; mi < 2; mi++) {
#pragma unroll
            for (int r = 0; r < 4; r++) {
                int m = m0 + mi * 16 + quad * 4 + r;
                float v = acc[mi][ni][r] + bv;
                if (MODE == 1) {
                    v = 0.5f * v * (1.0f + erff(v * 0.70710678118654752f));
                } else if (MODE == 2) {
                    v += res[(size_t)m * N + n];
                }
                C[(size_t)m * N + n] = v;
            }
        }
    }
}

// ---------------- fused split-S combine + output projection -----------------
__global__ __launch_bounds__(64, 4) void comb_gemm(
        const float* __restrict__ Opart, const float* __restrict__ mpart,
        const float* __restrict__ lpart,
        const float* __restrict__ W, const float* __restrict__ bias,
        const float* __restrict__ res,
        float* __restrict__ C) {
    __shared__ unsigned short As[32][264];
    const int t = threadIdx.x;
    const int fr = t & 15, quad = t >> 4;
    const int m0 = blockIdx.y * 32, n0 = blockIdx.x * 32;
    const int row = t & 31, half = t >> 5;

    {
        int m = m0 + row;
        int b = m / BQ, q = m % BQ;
#pragma unroll
        for (int h = half * 4; h < half * 4 + 4; h++) {
            float mv[NSPLIT], wsp[NSPLIT];
            float mstar = -1e30f;
#pragma unroll
            for (int sp = 0; sp < NSPLIT; sp++) {
                mv[sp] = mpart[((size_t)(b * NSPLIT + sp) * HH + h) * BQ + q];
                mstar = fmaxf(mstar, mv[sp]);
            }
            float lstar = 0.f;
#pragma unroll
            for (int sp = 0; sp < NSPLIT; sp++) {
                wsp[sp] = __expf(mv[sp] - mstar);
                lstar += lpart[((size_t)(b * NSPLIT + sp) * HH + h) * BQ + q] * wsp[sp];
            }
            float inv = 1.0f / lstar;
#pragma unroll
            for (int d = 0; d < HDD; d += 8) {
                float o[8] = {};
#pragma unroll
                for (int sp = 0; sp < NSPLIT; sp++) {
                    const float* op = Opart +
                        ((size_t)(b * NSPLIT + sp) * BQ + q) * DD + h * HDD + d;
                    float4 a = *(const float4*)op;
                    float4 b4 = *(const float4*)(op + 4);
                    o[0] += a.x * wsp[sp];  o[1] += a.y * wsp[sp];
                    o[2] += a.z * wsp[sp];  o[3] += a.w * wsp[sp];
                    o[4] += b4.x * wsp[sp]; o[5] += b4.y * wsp[sp];
                    o[6] += b4.z * wsp[sp]; o[7] += b4.w * wsp[sp];
                }
                uint4 pk;
                pk.x = (unsigned)f2bf(o[0] * inv) | ((unsigned)f2bf(o[1] * inv) << 16);
                pk.y = (unsigned)f2bf(o[2] * inv) | ((unsigned)f2bf(o[3] * inv) << 16);
                pk.z = (unsigned)f2bf(o[4] * inv) | ((unsigned)f2bf(o[5] * inv) << 16);
                pk.w = (unsigned)f2bf(o[6] * inv) | ((unsigned)f2bf(o[7] * inv) << 16);
                *(uint4*)&As[row][h * HDD + d] = pk;
            }
        }
    }
    __syncthreads();

    f32x4 acc[2][2] = {};
    const float* Wp0 = W + (size_t)(n0 + fr) * DD + quad * 8;
    const float* Wp1 = Wp0 + (size_t)16 * DD;
#pragma unroll
    for (int k0 = 0; k0 < DD; k0 += 32) {
        bf16x8 a0 = *(const bf16x8*)&As[fr][k0 + quad * 8];
        bf16x8 a1 = *(const bf16x8*)&As[16 + fr][k0 + quad * 8];
        bf16x8 w0 = load_bf8(Wp0 + k0);
        bf16x8 w1 = load_bf8(Wp1 + k0);
        acc[0][0] = __builtin_amdgcn_mfma_f32_16x16x32_bf16(a0, w0, acc[0][0], 0, 0, 0);
        acc[0][1] = __builtin_amdgcn_mfma_f32_16x16x32_bf16(a0, w1, acc[0][1], 0, 0, 0);
        acc[1][0] = __builtin_amdgcn_mfma_f32_16x16x32_bf16(a1, w0, acc[1][0], 0, 0, 0);
        acc[1][1] = __builtin_amdgcn_mfma_f32_16x16x32_bf16(a1, w1, acc[1][1], 0, 0, 0);
    }

#pragma unroll
    for (int ni = 0; ni < 2; ni++) {
        int n = n0 + ni * 16 + fr;
        float bv = bias[n];
#pragma unroll
        for (int mi = 0; mi < 2; mi++) {
#pragma unroll
            for (int r = 0; r < 4; r++) {
                int m = m0 + mi * 16 + quad * 4 + r;
                float v = acc[mi][ni][r] + bv + res[(size_t)m * DD + n];
                C[(size_t)m * DD + n] = v;
            }
        }
    }
}

// ---------------- one-wave MFMA GEMM: 32x32 tile/block, optional split-K ----
template<int KK, int SPLITK, int MODE>
__global__ __launch_bounds__(64, 4) void gemm_skinny2(
        const float* __restrict__ A, const float* __restrict__ W,
        const float* __restrict__ bias, const float* __restrict__ res,
        float* __restrict__ C, float* __restrict__ Cp, int N) {
    const int lane = threadIdx.x;
    const int fr = lane & 15, quad = lane >> 4;
    const int m0 = blockIdx.y * 32;
    const int n0 = blockIdx.x * 32;
    const int sk = blockIdx.z;
    const int KCH = KK / SPLITK;

    f32x4 acc[2][2] = {};
    const float* Ap0 = A + (size_t)(m0 + fr) * KK + sk * KCH + quad * 8;
    const float* Ap1 = Ap0 + (size_t)16 * KK;
    const float* Wp0 = W + (size_t)(n0 + fr) * KK + sk * KCH + quad * 8;
    const float* Wp1 = Wp0 + (size_t)16 * KK;

#pragma unroll
    for (int k0 = 0; k0 < KCH; k0 += 32) {
        bf16x8 a0 = load_bf8(Ap0 + k0);
        bf16x8 a1 = load_bf8(Ap1 + k0);
        bf16x8 w0 = load_bf8(Wp0 + k0);
        bf16x8 w1 = load_bf8(Wp1 + k0);
        acc[0][0] = __builtin_amdgcn_mfma_f32_16x16x32_bf16(a0, w0, acc[0][0], 0, 0, 0);
        acc[0][1] = __builtin_amdgcn_mfma_f32_16x16x32_bf16(a0, w1, acc[0][1], 0, 0, 0);
        acc[1][0] = __builtin_amdgcn_mfma_f32_16x16x32_bf16(a1, w0, acc[1][0], 0, 0, 0);
        acc[1][1] = __builtin_amdgcn_mfma_f32_16x16x32_bf16(a1, w1, acc[1][1], 0, 0, 0);
    }

    if (SPLITK == 1) {
#pragma unroll
        for (int ni = 0; ni < 2; ni++) {
            int n = n0 + ni * 16 + fr;
            float bv = bias[n];
#pragma unroll
            for (int mi = 0; mi < 2; mi++) {
#pragma unroll
                for (int r = 0; r < 4; r++) {
                    int m = m0 + mi * 16 + quad * 4 + r;
                    float v = acc[mi][ni][r] + bv;
                    if (MODE == 1) {
                        v = 0.5f * v * (1.0f + erff(v * 0.70710678118654752f));
                    } else if (MODE == 2) {
                        v += res[(size_t)m * N + n];
                    }
                    C[(size_t)m * N + n] = v;
                }
            }
        }
    } else {
        float* dst = Cp + (size_t)sk * MROWS * N;
#pragma unroll
        for (int ni = 0; ni < 2; ni++) {
            int n = n0 + ni * 16 + fr;
#pragma unroll
            for (int mi = 0; mi < 2; mi++) {
#pragma unroll
                for (int r = 0; r < 4; r++) {
                    int m = m0 + mi * 16 + quad * 4 + r;
                    dst[(size_t)m * N + n] = acc[mi][ni][r];
                }
            }
        }
    }
}

// ---------------- split-K combine: sum partials + epilogue ------------------
template<int SPLITK, int MODE>
__global__ void gemm_combine(const float* __restrict__ Cp,
                             const float* __restrict__ bias,
                             const float* __restrict__ res,
                             float* __restrict__ C, int N) {
    int m = blockIdx.x;
    for (int n = threadIdx.x; n < N; n += 256) {
        float v = bias[n];
#pragma unroll
        for (int sk = 0; sk < SPLITK; sk++)
            v += Cp[((size_t)sk * MROWS + m) * N + n];
        if (MODE == 1) {
            v = 0.5f * v * (1.0f + erff(v * 0.70710678118654752f));
        } else if (MODE == 2) {
            v += res[(size_t)m * N + n];
        }
        C[(size_t)m * N + n] = v;
    }
}

// ---------------- MFMA flash cross-attention, split-S, 64-q tiles -----------
#define QT 64
#define ST 128

__global__ __launch_bounds__(256) void cross_attn_mfma(
        const float* __restrict__ Qm,
        const unsigned short* __restrict__ Kb,
        const unsigned short* __restrict__ Vb,
        const unsigned* __restrict__ Mbits,
        float* __restrict__ Opart,
        float* __restrict__ mpart,
        float* __restrict__ lpart) {
    __shared__ unsigned short Qs[QT][40];
    __shared__ unsigned short Ks[ST][40];
    __shared__ unsigned short Vt[HDD][136];
    __shared__ unsigned short Ps[QT][136];
    __shared__ unsigned Mq[QT][4];
    __shared__ float red[QT][17];
    __shared__ float m_s[QT], alpha_s[QT], l_s[QT];

    const int qb = blockIdx.x, h = blockIdx.y;
    const int b = blockIdx.z / NSPLIT, sp = blockIdx.z % NSPLIT;
    const int t = threadIdx.x;
    const int w = t >> 6, lane = t & 63;
    const int fr = lane & 15, quad = lane >> 4;
    const int q0 = qb * QT;
    const int qlim = min(BQ - q0, QT);

    {
        int q = t >> 2, c0 = (t & 3) * 8;
        float4 v0 = make_float4(0.f, 0.f, 0.f, 0.f), v1 = v0;
        if (q < qlim) {
            const float* qp = Qm + (size_t)(b * BQ + q0 + q) * DD + h * HDD + c0;
            v0 = *(const float4*)qp;
            v1 = *(const float4*)(qp + 4);
        }
        const float sc = 0.17677669529663687f;
        uint4 pq;
        pq.x = (unsigned)f2bf(v0.x * sc) | ((unsigned)f2bf(v0.y * sc) << 16);
        pq.y = (unsigned)f2bf(v0.z * sc) | ((unsigned)f2bf(v0.w * sc) << 16);
        pq.z = (unsigned)f2bf(v1.x * sc) | ((unsigned)f2bf(v1.y * sc) << 16);
        pq.w = (unsigned)f2bf(v1.z * sc) | ((unsigned)f2bf(v1.w * sc) << 16);
        *(uint4*)&Qs[q][c0] = pq;
        if (t < QT) { m_s[t] = -1e30f; l_s[t] = 0.f; }
    }

    f32x4 oacc[2] = {};
    const unsigned short* Kbase = Kb + (((size_t)(b * HH + h)) * SS << 5);
    const unsigned short* Vbase = Vb + (((size_t)(b * HH + h)) * SS << 5);

    for (int s0 = sp * SCHUNK; s0 < (sp + 1) * SCHUNK; s0 += ST) {
        __syncthreads();
        {
            int r = t >> 1, half = t & 1;
            const unsigned short* kp = Kbase + ((size_t)(s0 + r) << 5) + half * 16;
            *(uint4*)&Ks[r][half * 16] = *(const uint4*)kp;
            *(uint4*)&Ks[r][half * 16 + 8] = *(const uint4*)(kp + 8);
            const unsigned short* vp = Vbase + ((size_t)(s0 + r) << 5) + half * 16;
            union { uint4 u; unsigned short s[8]; } v0, v1;
            v0.u = *(const uint4*)vp;
            v1.u = *(const uint4*)(vp + 8);
#pragma unroll
            for (int j = 0; j < 8; j++) Vt[half * 16 + j][r] = v0.s[j];
#pragma unroll
            for (int j = 0; j < 8; j++) Vt[half * 16 + 8 + j][r] = v1.s[j];
        }
        {
            int q = t >> 2, wd = t & 3;
            unsigned mword = 0xFFFFFFFFu;
            if (q < qlim)
                mword = Mbits[(size_t)(b * BQ + q0 + q) * 128 + (s0 >> 5) + wd];
            Mq[q][wd] = mword;
        }
        __syncthreads();

        bf16x8 af[2];
#pragma unroll
        for (int mt = 0; mt < 2; mt++)
            af[mt] = *(const bf16x8*)&Ks[w * 32 + mt * 16 + fr][quad * 8];
        f32x4 st[2][4];
#pragma unroll
        for (int nt = 0; nt < 4; nt++) {
            bf16x8 bq = *(const bf16x8*)&Qs[nt * 16 + fr][quad * 8];
#pragma unroll
            for (int mt = 0; mt < 2; mt++) {
                f32x4 z = {0.f, 0.f, 0.f, 0.f};
                st[mt][nt] = __builtin_amdgcn_mfma_f32_16x16x32_bf16(af[mt], bq, z, 0, 0, 0);
            }
        }

        float pmax[4] = {-1e30f, -1e30f, -1e30f, -1e30f};
#pragma unroll
        for (int nt = 0; nt < 4; nt++) {
            unsigned mword = Mq[nt * 16 + fr][w];
#pragma unroll
            for (int mt = 0; mt < 2; mt++)
#pragma unroll
                for (int r = 0; r < 4; r++) {
                    int bitpos = mt * 16 + quad * 4 + r;
                    float v = st[mt][nt][r];
                    if (!((mword >> bitpos) & 1u)) v -= 10000.f;
                    st[mt][nt][r] = v;
                    pmax[nt] = fmaxf(pmax[nt], v);
                }
        }
#pragma unroll
        for (int nt = 0; nt < 4; nt++)
            red[nt * 16 + fr][w * 4 + quad] = pmax[nt];
        __syncthreads();

        if (t < QT) {
            float mt_ = -1e30f;
#pragma unroll
            for (int k = 0; k < 16; k++) mt_ = fmaxf(mt_, red[t][k]);
            float mo = m_s[t], mn = fmaxf(mo, mt_);
            m_s[t] = mn;
            alpha_s[t] = __expf(mo - mn);
        }
        __syncthreads();

        float psum[4] = {0.f, 0.f, 0.f, 0.f};
#pragma unroll
        for (int nt = 0; nt < 4; nt++) {
            float mrow = m_s[nt * 16 + fr];
#pragma unroll
            for (int mt = 0; mt < 2; mt++) {
                float p0 = __expf(st[mt][nt][0] - mrow);
                float p1 = __expf(st[mt][nt][1] - mrow);
                float p2 = __expf(st[mt][nt][2] - mrow);
                float p3 = __expf(st[mt][nt][3] - mrow);
                psum[nt] += p0 + p1 + p2 + p3;
                ushort4 pk;
                pk.x = f2bf(p0); pk.y = f2bf(p1); pk.z = f2bf(p2); pk.w = f2bf(p3);
                *(ushort4*)&Ps[nt * 16 + fr][w * 32 + mt * 16 + quad * 4] = pk;
            }
        }
#pragma unroll
        for (int nt = 0; nt < 4; nt++)
            red[nt * 16 + fr][w * 4 + quad] = psum[nt];
        __syncthreads();

        if (t < QT) {
            float s = 0.f;
#pragma unroll
            for (int k = 0; k < 16; k++) s += red[t][k];
            l_s[t] = l_s[t] * alpha_s[t] + s;
        }

#pragma unroll
        for (int r = 0; r < 4; r++) {
            float a = alpha_s[w * 16 + quad * 4 + r];
            oacc[0][r] *= a; oacc[1][r] *= a;
        }
#pragma unroll
        for (int k0 = 0; k0 < ST; k0 += 32) {
            bf16x8 ap = *(const bf16x8*)&Ps[w * 16 + fr][k0 + quad * 8];
            bf16x8 bv0 = *(const bf16x8*)&Vt[fr][k0 + quad * 8];
            bf16x8 bv1 = *(const bf16x8*)&Vt[16 + fr][k0 + quad * 8];
            oacc[0] = __builtin_amdgcn_mfma_f32_16x16x32_bf16(ap, bv0, oacc[0], 0, 0, 0);
            oacc[1] = __builtin_amdgcn_mfma_f32_16x16x32_bf16(ap, bv1, oacc[1], 0, 0, 0);
        }
    }
    __syncthreads();

    int part = b * NSPLIT + sp;
    if (t < qlim) {
        mpart[((size_t)part * HH + h) * BQ + q0 + t] = m_s[t];
        lpart[((size_t)part * HH + h) * BQ + q0 + t] = l_s[t];
    }
#pragma unroll
    for (int nd = 0; nd < 2; nd++) {
#pragma unroll
        for (int r = 0; r < 4; r++) {
            int q = w * 16 + quad * 4 + r;
            if (q < qlim)
                Opart[((size_t)part * BQ + q0 + q) * DD + h * HDD + nd * 16 + fr] = oacc[nd][r];
        }
    }
}

// ---------------- self-attention (S=Q=100) ----------------------------------
__global__ void attn_kernel(const float* __restrict__ Qm, int sq, int qo0,
                            const float* __restrict__ Km, int sk, int ko0,
                            const float* __restrict__ Vm, int sv, int vo0,
                            float* __restrict__ Out, int so, int oo0,
                            int Slen, int Qlen, float scale) {
    int q = blockIdx.x, h = blockIdx.y, b = blockIdx.z;
    int tid = threadIdx.x;
    __shared__ float qv[32];
    __shared__ float sc[128];
    __shared__ float red[256];
    __shared__ float part[8][33];
    int qrow = b * Qlen + q;
    if (tid < 32) qv[tid] = Qm[(size_t)qrow * sq + qo0 + h * HDD + tid] * scale;
    __syncthreads();

    float lmax = -1e30f;
    for (int s = tid; s < Slen; s += 256) {
        const float* kp = Km + (size_t)(b * Slen + s) * sk + ko0 + h * HDD;
        float dot = 0.f;
#pragma unroll
        for (int d = 0; d < HDD; d += 4) {
            float4 k4 = *(const float4*)(kp + d);
            dot += qv[d] * k4.x + qv[d + 1] * k4.y + qv[d + 2] * k4.z + qv[d + 3] * k4.w;
        }
        sc[s] = dot;
        lmax = fmaxf(lmax, dot);
    }
    red[tid] = lmax; __syncthreads();
    for (int off = 128; off > 0; off >>= 1) {
        if (tid < off) red[tid] = fmaxf(red[tid], red[tid + off]);
        __syncthreads();
    }
    float m = red[0];
    __syncthreads();
    float lsum = 0.f;
    for (int s = tid; s < Slen; s += 256) {
        float e = __expf(sc[s] - m);
        sc[s] = e;
        lsum += e;
    }
    red[tid] = lsum; __syncthreads();
    for (int off = 128; off > 0; off >>= 1) {
        if (tid < off) red[tid] += red[tid + off];
        __syncthreads();
    }
    float inv = 1.0f / red[0];

    int d = tid & 31, g = tid >> 5;
    float acc = 0.f;
    for (int s = g; s < Slen; s += 8)
        acc += sc[s] * Vm[(size_t)(b * Slen + s) * sv + vo0 + h * HDD + d];
    part[g][d] = acc; __syncthreads();
    if (g == 0) {
        float t = 0.f;
#pragma unroll
        for (int gg = 0; gg < 8; gg++) t += part[gg][d];
        Out[(size_t)qrow * so + oo0 + h * HDD + d] = t * inv;
    }
}

extern "C" void kernel_launch(void* const* d_in, const int* in_sizes, int n_in,
                              void* d_out, int out_size, void* d_ws, size_t ws_size,
                              hipStream_t stream) {
    const float* queries    = (const float*)d_in[0];
    const float* pixel_feat = (const float*)d_in[1];
    const float* prev_mask  = (const float*)d_in[2];
    const float* cross_in_w  = (const float*)d_in[3];
    const float* cross_in_b  = (const float*)d_in[4];
    const float* cross_out_w = (const float*)d_in[5];
    const float* cross_out_b = (const float*)d_in[6];
    const float* self_in_w   = (const float*)d_in[7];
    const float* self_in_b   = (const float*)d_in[8];
    const float* self_out_w  = (const float*)d_in[9];
    const float* self_out_b  = (const float*)d_in[10];
    const float* ln_cross_g  = (const float*)d_in[11];
    const float* ln_cross_b  = (const float*)d_in[12];
    const float* ln_self_g   = (const float*)d_in[13];
    const float* ln_self_b   = (const float*)d_in[14];
    const float* ln_ffn_g    = (const float*)d_in[15];
    const float* ln_ffn_b    = (const float*)d_in[16];
    const float* ffn_w1 = (const float*)d_in[17];
    const float* ffn_b1 = (const float*)d_in[18];
    const float* ffn_w2 = (const float*)d_in[19];
    const float* ffn_b2 = (const float*)d_in[20];
    float* out = (float*)d_out;

    const int NQ = SB * BQ;        // 800
    const int NK = SB * SS;        // 32768

    float* ws = (float*)d_ws;
    unsigned* Mbits = (unsigned*)ws;   ws += (size_t)NQ * 128;
    float* q_cross  = ws;              ws += (size_t)NQ * DD;
    unsigned short* Kbk = (unsigned short*)ws;
    ws += (size_t)NK * DD / 2;
    unsigned short* Vbk = (unsigned short*)ws;
    ws += (size_t)NK * DD / 2;
    float* queries1 = ws;              ws += (size_t)NQ * DD;
    float* qkv      = ws;              ws += (size_t)NQ * 3 * DD;
    float* attn2    = ws;              ws += (size_t)NQ * DD;
    float* queries2 = ws;              ws += (size_t)NQ * DD;
    float* ffn_h    = ws;              ws += (size_t)NQ * 4 * DD;
    float* Csplit   = ws;              ws += (size_t)4 * MROWS * DD;
    float* Opart    = ws;              ws += (size_t)SB * NSPLIT * BQ * DD;
    float* mpart    = ws;              ws += (size_t)SB * NSPLIT * HH * BQ;
    float* lpart    = ws;              ws += (size_t)SB * NSPLIT * HH * BQ;

    const float scale = 0.17677669529663687f;

    // ---- stage1: KV proj + maskpack + LN/Q-proj (one dispatch) ----
    stage1<<<1874, 256, 0, stream>>>(
        queries, ln_cross_g, ln_cross_b, cross_in_w, cross_in_b, q_cross,
        pixel_feat, Kbk, Vbk, prev_mask, Mbits);

    // ---- cross attention ----
    cross_attn_mfma<<<dim3(2, HH, SB * NSPLIT), 256, 0, stream>>>(
        q_cross, Kbk, Vbk, Mbits, Opart, mpart, lpart);
    comb_gemm<<<dim3(8, 25), 64, 0, stream>>>(
        Opart, mpart, lpart, cross_out_w, cross_out_b, queries, queries1);

    // ---- self attention ----
    ln_gemm<0><<<dim3(24, 25), 64, 0, stream>>>(
        queries1, ln_self_g, ln_self_b, self_in_w, self_in_b, nullptr,
        qkv, 3 * DD);
    attn_kernel<<<dim3(BQ, HH, SB), 256, 0, stream>>>(
        qkv, 3 * DD, 0, qkv, 3 * DD, DD, qkv, 3 * DD, 2 * DD,
        attn2, DD, 0, BQ, BQ, scale);
    gemm_skinny2<256, 1, 2><<<dim3(8, 25), 64, 0, stream>>>(
        attn2, self_out_w, self_out_b, queries1, queries2, nullptr, DD);

    // ---- FFN ----
    ln_gemm<1><<<dim3(32, 25), 64, 0, stream>>>(
        queries2, ln_ffn_g, ln_ffn_b, ffn_w1, ffn_b1, nullptr,
        ffn_h, 4 * DD);
    gemm_skinny2<1024, 4, 2><<<dim3(8, 25, 4), 64, 0, stream>>>(
        ffn_h, ffn_w2, ffn_b2, nullptr, nullptr, Csplit, DD);
    gemm_combine<4, 2><<<MROWS, 256, 0, stream>>>(
        Csplit, ffn_b2, queries2, out, DD);
}

// Round 12
// 260.241 us; speedup vs baseline: 1.2114x; 1.0478x over previous
//
#include <hip/hip_runtime.h>
#include <hip/hip_bf16.h>
#include <math.h>

#define BQ 100
#define SB 8
#define SS 4096
#define DD 256
#define HH 8
#define HDD 32
#define NSPLIT 4
#define SCHUNK (SS / NSPLIT)   // 1024
#define MROWS 800              // SB*BQ

typedef __attribute__((ext_vector_type(8))) short bf16x8;
typedef __attribute__((ext_vector_type(4))) float f32x4;

__device__ inline unsigned short f2bf(float f) {
    union { float f; unsigned u; } v; v.f = f;
    unsigned r = v.u + 0x7fff + ((v.u >> 16) & 1);
    return (unsigned short)(r >> 16);
}

// HW packed fp32x2 -> bf16x2 (v_cvt_pk_bf16_f32 on gfx950), RNE
__device__ inline unsigned pkbf(float x, float y) {
    union { __hip_bfloat162 h; unsigned u; } c;
    c.h = __float22bfloat162_rn(make_float2(x, y));
    return c.u;
}

__device__ inline bf16x8 load_bf8(const float* p) {
    float4 a = *(const float4*)p;
    float4 b = *(const float4*)(p + 4);
    union { unsigned u[4]; bf16x8 v; } r;
    r.u[0] = pkbf(a.x, a.y); r.u[1] = pkbf(a.z, a.w);
    r.u[2] = pkbf(b.x, b.y); r.u[3] = pkbf(b.z, b.w);
    return r.v;
}

#define TM 128
#define TN 128
#define TK 32
#define LSTR 40

// ============ stage1: fused {KV projection | maskpack | LN+Q-projection} ====
// grid.x: [0,1024) KV proj tiles; [1024,1824) maskpack rows; [1824,1874) LN+Qproj.
__global__ __launch_bounds__(256, 2) void stage1(
        const float* __restrict__ queries,
        const float* __restrict__ ln_g, const float* __restrict__ ln_b,
        const float* __restrict__ cw, const float* __restrict__ cb,
        float* __restrict__ q_cross,
        const float* __restrict__ pixel_feat,
        unsigned short* __restrict__ Kb, unsigned short* __restrict__ Vb,
        const float* __restrict__ mask, unsigned* __restrict__ Mbits) {
    __shared__ __align__(16) char smem[21504];
    const int bid = blockIdx.x;
    const int t = threadIdx.x;

    if (bid < 1024) {
        typedef unsigned short (*tile_t)[LSTR];
        tile_t As = (tile_t)smem;
        tile_t Bs = (tile_t)(smem + 128 * LSTR * 2);
        const float* A = pixel_feat;
        const float* W = cw + (size_t)DD * DD;
        const float* bias = cb + DD;
        int m0 = (bid >> 2) * TM, n0 = (bid & 3) * TN;
        int wave = t / 64, lane = t % 64;
        int wm = (wave % 2) * 64, wn = (wave / 2) * 64;
        int lr = t / 4, lc = (t % 4) * 8;
        int fr = lane % 16, quad = lane / 16;
        f32x4 acc[4][4] = {};
        for (int k0 = 0; k0 < DD; k0 += TK) {
            __syncthreads();
#pragma unroll
            for (int half = 0; half < 2; half++) {
                int r = lr + half * 64;
                float4 a0 = *(const float4*)(A + (size_t)(m0 + r) * DD + k0 + lc);
                float4 a1 = *(const float4*)(A + (size_t)(m0 + r) * DD + k0 + lc + 4);
                uint4 pa;
                pa.x = pkbf(a0.x, a0.y); pa.y = pkbf(a0.z, a0.w);
                pa.z = pkbf(a1.x, a1.y); pa.w = pkbf(a1.z, a1.w);
                *(uint4*)&As[r][lc] = pa;
                float4 b0 = *(const float4*)(W + (size_t)(n0 + r) * DD + k0 + lc);
                float4 b1 = *(const float4*)(W + (size_t)(n0 + r) * DD + k0 + lc + 4);
                uint4 pb;
                pb.x = pkbf(b0.x, b0.y); pb.y = pkbf(b0.z, b0.w);
                pb.z = pkbf(b1.x, b1.y); pb.w = pkbf(b1.z, b1.w);
                *(uint4*)&Bs[r][lc] = pb;
            }
            __syncthreads();
            bf16x8 af[4], bf[4];
#pragma unroll
            for (int mi = 0; mi < 4; mi++)
                af[mi] = *(const bf16x8*)&As[wm + mi * 16 + fr][quad * 8];
#pragma unroll
            for (int ni = 0; ni < 4; ni++)
                bf[ni] = *(const bf16x8*)&Bs[wn + ni * 16 + fr][quad * 8];
#pragma unroll
            for (int mi = 0; mi < 4; mi++)
#pragma unroll
                for (int ni = 0; ni < 4; ni++)
                    acc[mi][ni] = __builtin_amdgcn_mfma_f32_16x16x32_bf16(
                        af[mi], bf[ni], acc[mi][ni], 0, 0, 0);
        }
#pragma unroll
        for (int ni = 0; ni < 4; ni++) {
            int n = n0 + wn + ni * 16 + fr;
            float bv = bias[n];
            unsigned short* dst = (n < 256) ? Kb : Vb;
            int hh = (n >> 5) & 7, d = n & 31;
#pragma unroll
            for (int mi = 0; mi < 4; mi++) {
#pragma unroll
                for (int r = 0; r < 4; r++) {
                    int m = m0 + wm + mi * 16 + quad * 4 + r;
                    int bb = m >> 12, s = m & (SS - 1);
                    dst[((((size_t)bb * HH + hh) * SS + s) << 5) + d] =
                        f2bf(acc[mi][ni][r] + bv);
                }
            }
        }
    } else if (bid < 1824) {
        int row = bid - 1024;
        unsigned* words = (unsigned*)smem;
        unsigned* orred = (unsigned*)(smem + 512);
        int w = t >> 6, lane = t & 63;
        unsigned lor = 0;
        for (int i = 0; i < 16; i++) {
            int s = (w * 16 + i) * 64 + lane;
            unsigned long long bal = __ballot(mask[(size_t)row * SS + s] > 0.f);
            if (lane == 0) {
                words[(w * 16 + i) * 2] = (unsigned)bal;
                words[(w * 16 + i) * 2 + 1] = (unsigned)(bal >> 32);
            }
            lor |= (unsigned)(bal | (bal >> 32));
        }
        if (lane == 0) orred[w] = lor;
        __syncthreads();
        unsigned anyv = orred[0] | orred[1] | orred[2] | orred[3];
        if (t < 128) Mbits[(size_t)row * 128 + t] = anyv ? words[t] : 0xFFFFFFFFu;
    } else {
        typedef unsigned short (*arow_t)[264];
        arow_t Aq = (arow_t)smem;
        float* mu_s = (float*)(smem + 16896);
        float* rs_s = mu_s + 32;
        float (*prt)[8][2] = (float(*)[8][2])(rs_s + 32);
        int idx = bid - 1824;
        int nq = idx & 1, my = idx >> 1;
        int m0 = my * 32;
        int row = t & 31, cs = t >> 5;
        const float* xp = queries + (size_t)(m0 + row) * DD + cs * 32;
        float s = 0.f, ss = 0.f;
#pragma unroll
        for (int c = 0; c < 32; c += 4) {
            float4 v = *(const float4*)(xp + c);
            s += v.x + v.y + v.z + v.w;
            ss += v.x * v.x + v.y * v.y + v.z * v.z + v.w * v.w;
        }
        prt[row][cs][0] = s; prt[row][cs][1] = ss;
        __syncthreads();
        if (t < 32) {
            float sum = 0.f, sq = 0.f;
#pragma unroll
            for (int k = 0; k < 8; k++) { sum += prt[t][k][0]; sq += prt[t][k][1]; }
            float mu = sum * (1.0f / DD);
            float var = sq * (1.0f / DD) - mu * mu;
            mu_s[t] = mu;
            rs_s[t] = rsqrtf(var + 1e-5f);
        }
        __syncthreads();
        {
            float mu = mu_s[row], r = rs_s[row];
            int col0 = cs * 32;
#pragma unroll
            for (int c = 0; c < 32; c += 8) {
                int col = col0 + c;
                float4 v0 = *(const float4*)(xp + c);
                float4 v1 = *(const float4*)(xp + c + 4);
                float4 g0 = *(const float4*)(ln_g + col);
                float4 g1 = *(const float4*)(ln_g + col + 4);
                float4 b0 = *(const float4*)(ln_b + col);
                float4 b1 = *(const float4*)(ln_b + col + 4);
                uint4 pk;
                pk.x = pkbf((v0.x - mu) * r * g0.x + b0.x, (v0.y - mu) * r * g0.y + b0.y);
                pk.y = pkbf((v0.z - mu) * r * g0.z + b0.z, (v0.w - mu) * r * g0.w + b0.w);
                pk.z = pkbf((v1.x - mu) * r * g1.x + b1.x, (v1.y - mu) * r * g1.y + b1.y);
                pk.w = pkbf((v1.z - mu) * r * g1.z + b1.z, (v1.w - mu) * r * g1.w + b1.w);
                *(uint4*)&Aq[row][col] = pk;
            }
        }
        __syncthreads();
        int w = t >> 6, lane = t & 63;
        int fr = lane & 15, quad = lane >> 4;
        int n0 = nq * 128 + w * 32;
        f32x4 acc[2][2] = {};
        const float* Wp0 = cw + (size_t)(n0 + fr) * DD + quad * 8;
        const float* Wp1 = Wp0 + (size_t)16 * DD;
#pragma unroll
        for (int k0 = 0; k0 < DD; k0 += 32) {
            bf16x8 a0 = *(const bf16x8*)&Aq[fr][k0 + quad * 8];
            bf16x8 a1 = *(const bf16x8*)&Aq[16 + fr][k0 + quad * 8];
            bf16x8 w0 = load_bf8(Wp0 + k0);
            bf16x8 w1 = load_bf8(Wp1 + k0);
            acc[0][0] = __builtin_amdgcn_mfma_f32_16x16x32_bf16(a0, w0, acc[0][0], 0, 0, 0);
            acc[0][1] = __builtin_amdgcn_mfma_f32_16x16x32_bf16(a0, w1, acc[0][1], 0, 0, 0);
            acc[1][0] = __builtin_amdgcn_mfma_f32_16x16x32_bf16(a1, w0, acc[1][0], 0, 0, 0);
            acc[1][1] = __builtin_amdgcn_mfma_f32_16x16x32_bf16(a1, w1, acc[1][1], 0, 0, 0);
        }
#pragma unroll
        for (int ni = 0; ni < 2; ni++) {
            int n = n0 + ni * 16 + fr;
            float bv = cb[n];
#pragma unroll
            for (int mi = 0; mi < 2; mi++) {
#pragma unroll
                for (int r = 0; r < 4; r++) {
                    int m = m0 + mi * 16 + quad * 4 + r;
                    q_cross[(size_t)m * DD + n] = acc[mi][ni][r] + bv;
                }
            }
        }
    }
}

// ---------------- fused LayerNorm + one-wave MFMA GEMM ----------------------
template<int MODE>
__global__ __launch_bounds__(64, 4) void ln_gemm(
        const float* __restrict__ X, const float* __restrict__ gam,
        const float* __restrict__ bet,
        const float* __restrict__ W, const float* __restrict__ bias,
        const float* __restrict__ res,
        float* __restrict__ C, int N) {
    __shared__ unsigned short As[32][264];
    __shared__ float mu_s[32], rs_s[32];
    __shared__ float prt[32][2][2];
    const int t = threadIdx.x;
    const int fr = t & 15, quad = t >> 4;
    const int m0 = blockIdx.y * 32, n0 = blockIdx.x * 32;
    const int row = t & 31, half = t >> 5;

    const float* xp = X + (size_t)(m0 + row) * DD + half * 128;
    float s = 0.f, ss = 0.f;
#pragma unroll
    for (int c = 0; c < 128; c += 4) {
        float4 v = *(const float4*)(xp + c);
        s += v.x + v.y + v.z + v.w;
        ss += v.x * v.x + v.y * v.y + v.z * v.z + v.w * v.w;
    }
    prt[row][half][0] = s;
    prt[row][half][1] = ss;
    __syncthreads();
    if (t < 32) {
        float sum = prt[t][0][0] + prt[t][1][0];
        float sq  = prt[t][0][1] + prt[t][1][1];
        float mu = sum * (1.0f / DD);
        float var = sq * (1.0f / DD) - mu * mu;
        mu_s[t] = mu;
        rs_s[t] = rsqrtf(var + 1e-5f);
    }
    __syncthreads();
    {
        float mu = mu_s[row], r = rs_s[row];
#pragma unroll
        for (int c = 0; c < 128; c += 8) {
            int col = half * 128 + c;
            float4 v0 = *(const float4*)(xp + c);
            float4 v1 = *(const float4*)(xp + c + 4);
            float4 g0 = *(const float4*)(gam + col);
            float4 g1 = *(const float4*)(gam + col + 4);
            float4 b0 = *(const float4*)(bet + col);
            float4 b1 = *(const float4*)(bet + col + 4);
            uint4 pk;
            pk.x = pkbf((v0.x - mu) * r * g0.x + b0.x, (v0.y - mu) * r * g0.y + b0.y);
            pk.y = pkbf((v0.z - mu) * r * g0.z + b0.z, (v0.w - mu) * r * g0.w + b0.w);
            pk.z = pkbf((v1.x - mu) * r * g1.x + b1.x, (v1.y - mu) * r * g1.y + b1.y);
            pk.w = pkbf((v1.z - mu) * r * g1.z + b1.z, (v1.w - mu) * r * g1.w + b1.w);
            *(uint4*)&As[row][col] = pk;
        }
    }
    __syncthreads();

    f32x4 acc[2][2] = {};
    const float* Wp0 = W + (size_t)(n0 + fr) * DD + quad * 8;
    const float* Wp1 = Wp0 + (size_t)16 * DD;
#pragma unroll
    for (int k0 = 0; k0 < DD; k0 += 32) {
        bf16x8 a0 = *(const bf16x8*)&As[fr][k0 + quad * 8];
        bf16x8 a1 = *(const bf16x8*)&As[16 + fr][k0 + quad * 8];
        bf16x8 w0 = load_bf8(Wp0 + k0);
        bf16x8 w1 = load_bf8(Wp1 + k0);
        acc[0][0] = __builtin_amdgcn_mfma_f32_16x16x32_bf16(a0, w0, acc[0][0], 0, 0, 0);
        acc[0][1] = __builtin_amdgcn_mfma_f32_16x16x32_bf16(a0, w1, acc[0][1], 0, 0, 0);
        acc[1][0] = __builtin_amdgcn_mfma_f32_16x16x32_bf16(a1, w0, acc[1][0], 0, 0, 0);
        acc[1][1] = __builtin_amdgcn_mfma_f32_16x16x32_bf16(a1, w1, acc[1][1], 0, 0, 0);
    }

#pragma unroll
    for (int ni = 0; ni < 2; ni++) {
        int n = n0 + ni * 16 + fr;
        float bv = bias[n];
#pragma unroll
        for (int mi = 0; mi < 2; mi++) {
#pragma unroll
            for (int r = 0; r < 4; r++) {
                int m = m0 + mi * 16 + quad * 4 + r;
                float v = acc[mi][ni][r] + bv;
                if (MODE == 1) {
                    v = 0.5f * v * (1.0f + erff(v * 0.70710678118654752f));
                } else if (MODE == 2) {
                    v += res[(size_t)m * N + n];
                }
                C[(size_t)m * N + n] = v;
            }
        }
    }
}

// ---------------- fused split-S combine + output projection -----------------
__global__ __launch_bounds__(64, 4) void comb_gemm(
        const float* __restrict__ Opart, const float* __restrict__ mpart,
        const float* __restrict__ lpart,
        const float* __restrict__ W, const float* __restrict__ bias,
        const float* __restrict__ res,
        float* __restrict__ C) {
    __shared__ unsigned short As[32][264];
    const int t = threadIdx.x;
    const int fr = t & 15, quad = t >> 4;
    const int m0 = blockIdx.y * 32, n0 = blockIdx.x * 32;
    const int row = t & 31, half = t >> 5;

    {
        int m = m0 + row;
        int b = m / BQ, q = m % BQ;
#pragma unroll
        for (int h = half * 4; h < half * 4 + 4; h++) {
            float mv[NSPLIT], wsp[NSPLIT];
            float mstar = -1e30f;
#pragma unroll
            for (int sp = 0; sp < NSPLIT; sp++) {
                mv[sp] = mpart[((size_t)(b * NSPLIT + sp) * HH + h) * BQ + q];
                mstar = fmaxf(mstar, mv[sp]);
            }
            float lstar = 0.f;
#pragma unroll
            for (int sp = 0; sp < NSPLIT; sp++) {
                wsp[sp] = __expf(mv[sp] - mstar);
                lstar += lpart[((size_t)(b * NSPLIT + sp) * HH + h) * BQ + q] * wsp[sp];
            }
            float inv = 1.0f / lstar;
#pragma unroll
            for (int d = 0; d < HDD; d += 8) {
                float o[8] = {};
#pragma unroll
                for (int sp = 0; sp < NSPLIT; sp++) {
                    const float* op = Opart +
                        ((size_t)(b * NSPLIT + sp) * BQ + q) * DD + h * HDD + d;
                    float4 a = *(const float4*)op;
                    float4 b4 = *(const float4*)(op + 4);
                    o[0] += a.x * wsp[sp];  o[1] += a.y * wsp[sp];
                    o[2] += a.z * wsp[sp];  o[3] += a.w * wsp[sp];
                    o[4] += b4.x * wsp[sp]; o[5] += b4.y * wsp[sp];
                    o[6] += b4.z * wsp[sp]; o[7] += b4.w * wsp[sp];
                }
                uint4 pk;
                pk.x = pkbf(o[0] * inv, o[1] * inv);
                pk.y = pkbf(o[2] * inv, o[3] * inv);
                pk.z = pkbf(o[4] * inv, o[5] * inv);
                pk.w = pkbf(o[6] * inv, o[7] * inv);
                *(uint4*)&As[row][h * HDD + d] = pk;
            }
        }
    }
    __syncthreads();

    f32x4 acc[2][2] = {};
    const float* Wp0 = W + (size_t)(n0 + fr) * DD + quad * 8;
    const float* Wp1 = Wp0 + (size_t)16 * DD;
#pragma unroll
    for (int k0 = 0; k0 < DD; k0 += 32) {
        bf16x8 a0 = *(const bf16x8*)&As[fr][k0 + quad * 8];
        bf16x8 a1 = *(const bf16x8*)&As[16 + fr][k0 + quad * 8];
        bf16x8 w0 = load_bf8(Wp0 + k0);
        bf16x8 w1 = load_bf8(Wp1 + k0);
        acc[0][0] = __builtin_amdgcn_mfma_f32_16x16x32_bf16(a0, w0, acc[0][0], 0, 0, 0);
        acc[0][1] = __builtin_amdgcn_mfma_f32_16x16x32_bf16(a0, w1, acc[0][1], 0, 0, 0);
        acc[1][0] = __builtin_amdgcn_mfma_f32_16x16x32_bf16(a1, w0, acc[1][0], 0, 0, 0);
        acc[1][1] = __builtin_amdgcn_mfma_f32_16x16x32_bf16(a1, w1, acc[1][1], 0, 0, 0);
    }

#pragma unroll
    for (int ni = 0; ni < 2; ni++) {
        int n = n0 + ni * 16 + fr;
        float bv = bias[n];
#pragma unroll
        for (int mi = 0; mi < 2; mi++) {
#pragma unroll
            for (int r = 0; r < 4; r++) {
                int m = m0 + mi * 16 + quad * 4 + r;
                float v = acc[mi][ni][r] + bv + res[(size_t)m * DD + n];
                C[(size_t)m * DD + n] = v;
            }
        }
    }
}

// ---------------- one-wave MFMA GEMM: 32x32 tile/block, optional split-K ----
template<int KK, int SPLITK, int MODE>
__global__ __launch_bounds__(64, 4) void gemm_skinny2(
        const float* __restrict__ A, const float* __restrict__ W,
        const float* __restrict__ bias, const float* __restrict__ res,
        float* __restrict__ C, float* __restrict__ Cp, int N) {
    const int lane = threadIdx.x;
    const int fr = lane & 15, quad = lane >> 4;
    const int m0 = blockIdx.y * 32;
    const int n0 = blockIdx.x * 32;
    const int sk = blockIdx.z;
    const int KCH = KK / SPLITK;

    f32x4 acc[2][2] = {};
    const float* Ap0 = A + (size_t)(m0 + fr) * KK + sk * KCH + quad * 8;
    const float* Ap1 = Ap0 + (size_t)16 * KK;
    const float* Wp0 = W + (size_t)(n0 + fr) * KK + sk * KCH + quad * 8;
    const float* Wp1 = Wp0 + (size_t)16 * KK;

#pragma unroll
    for (int k0 = 0; k0 < KCH; k0 += 32) {
        bf16x8 a0 = load_bf8(Ap0 + k0);
        bf16x8 a1 = load_bf8(Ap1 + k0);
        bf16x8 w0 = load_bf8(Wp0 + k0);
        bf16x8 w1 = load_bf8(Wp1 + k0);
        acc[0][0] = __builtin_amdgcn_mfma_f32_16x16x32_bf16(a0, w0, acc[0][0], 0, 0, 0);
        acc[0][1] = __builtin_amdgcn_mfma_f32_16x16x32_bf16(a0, w1, acc[0][1], 0, 0, 0);
        acc[1][0] = __builtin_amdgcn_mfma_f32_16x16x32_bf16(a1, w0, acc[1][0], 0, 0, 0);
        acc[1][1] = __builtin_amdgcn_mfma_f32_16x16x32_bf16(a1, w1, acc[1][1], 0, 0, 0);
    }

    if (SPLITK == 1) {
#pragma unroll
        for (int ni = 0; ni < 2; ni++) {
            int n = n0 + ni * 16 + fr;
            float bv = bias[n];
#pragma unroll
            for (int mi = 0; mi < 2; mi++) {
#pragma unroll
                for (int r = 0; r < 4; r++) {
                    int m = m0 + mi * 16 + quad * 4 + r;
                    float v = acc[mi][ni][r] + bv;
                    if (MODE == 1) {
                        v = 0.5f * v * (1.0f + erff(v * 0.70710678118654752f));
                    } else if (MODE == 2) {
                        v += res[(size_t)m * N + n];
                    }
                    C[(size_t)m * N + n] = v;
                }
            }
        }
    } else {
        float* dst = Cp + (size_t)sk * MROWS * N;
#pragma unroll
        for (int ni = 0; ni < 2; ni++) {
            int n = n0 + ni * 16 + fr;
#pragma unroll
            for (int mi = 0; mi < 2; mi++) {
#pragma unroll
                for (int r = 0; r < 4; r++) {
                    int m = m0 + mi * 16 + quad * 4 + r;
                    dst[(size_t)m * N + n] = acc[mi][ni][r];
                }
            }
        }
    }
}

// ---------------- split-K combine: sum partials + epilogue ------------------
template<int SPLITK, int MODE>
__global__ void gemm_combine(const float* __restrict__ Cp,
                             const float* __restrict__ bias,
                             const float* __restrict__ res,
                             float* __restrict__ C, int N) {
    int m = blockIdx.x;
    for (int n = threadIdx.x; n < N; n += 256) {
        float v = bias[n];
#pragma unroll
        for (int sk = 0; sk < SPLITK; sk++)
            v += Cp[((size_t)sk * MROWS + m) * N + n];
        if (MODE == 1) {
            v = 0.5f * v * (1.0f + erff(v * 0.70710678118654752f));
        } else if (MODE == 2) {
            v += res[(size_t)m * N + n];
        }
        C[(size_t)m * N + n] = v;
    }
}

// ---------------- MFMA flash cross-attention, split-S, 64-q tiles -----------
#define QT 64
#define ST 128

__global__ __launch_bounds__(256) void cross_attn_mfma(
        const float* __restrict__ Qm,
        const unsigned short* __restrict__ Kb,
        const unsigned short* __restrict__ Vb,
        const unsigned* __restrict__ Mbits,
        float* __restrict__ Opart,
        float* __restrict__ mpart,
        float* __restrict__ lpart) {
    __shared__ unsigned short Qs[QT][40];
    __shared__ unsigned short Ks[ST][40];
    __shared__ unsigned short Vt[HDD][136];
    __shared__ unsigned short Ps[QT][136];
    __shared__ unsigned Mq[QT][4];
    __shared__ float red[QT][17];
    __shared__ float m_s[QT], alpha_s[QT], l_s[QT];

    const int qb = blockIdx.x, h = blockIdx.y;
    const int b = blockIdx.z / NSPLIT, sp = blockIdx.z % NSPLIT;
    const int t = threadIdx.x;
    const int w = t >> 6, lane = t & 63;
    const int fr = lane & 15, quad = lane >> 4;
    const int q0 = qb * QT;
    const int qlim = min(BQ - q0, QT);

    {
        int q = t >> 2, c0 = (t & 3) * 8;
        float4 v0 = make_float4(0.f, 0.f, 0.f, 0.f), v1 = v0;
        if (q < qlim) {
            const float* qp = Qm + (size_t)(b * BQ + q0 + q) * DD + h * HDD + c0;
            v0 = *(const float4*)qp;
            v1 = *(const float4*)(qp + 4);
        }
        const float sc = 0.17677669529663687f;
        uint4 pq;
        pq.x = pkbf(v0.x * sc, v0.y * sc);
        pq.y = pkbf(v0.z * sc, v0.w * sc);
        pq.z = pkbf(v1.x * sc, v1.y * sc);
        pq.w = pkbf(v1.z * sc, v1.w * sc);
        *(uint4*)&Qs[q][c0] = pq;
        if (t < QT) { m_s[t] = -1e30f; l_s[t] = 0.f; }
    }

    f32x4 oacc[2] = {};
    const unsigned short* Kbase = Kb + (((size_t)(b * HH + h)) * SS << 5);
    const unsigned short* Vbase = Vb + (((size_t)(b * HH + h)) * SS << 5);

    for (int s0 = sp * SCHUNK; s0 < (sp + 1) * SCHUNK; s0 += ST) {
        __syncthreads();
        {
            int r = t >> 1, half = t & 1;
            const unsigned short* kp = Kbase + ((size_t)(s0 + r) << 5) + half * 16;
            *(uint4*)&Ks[r][half * 16] = *(const uint4*)kp;
            *(uint4*)&Ks[r][half * 16 + 8] = *(const uint4*)(kp + 8);
            const unsigned short* vp = Vbase + ((size_t)(s0 + r) << 5) + half * 16;
            union { uint4 u; unsigned short s[8]; } v0, v1;
            v0.u = *(const uint4*)vp;
            v1.u = *(const uint4*)(vp + 8);
#pragma unroll
            for (int j = 0; j < 8; j++) Vt[half * 16 + j][r] = v0.s[j];
#pragma unroll
            for (int j = 0; j < 8; j++) Vt[half * 16 + 8 + j][r] = v1.s[j];
        }
        {
            int q = t >> 2, wd = t & 3;
            unsigned mword = 0xFFFFFFFFu;
            if (q < qlim)
                mword = Mbits[(size_t)(b * BQ + q0 + q) * 128 + (s0 >> 5) + wd];
            Mq[q][wd] = mword;
        }
        __syncthreads();

        bf16x8 af[2];
#pragma unroll
        for (int mt = 0; mt < 2; mt++)
            af[mt] = *(const bf16x8*)&Ks[w * 32 + mt * 16 + fr][quad * 8];
        f32x4 st[2][4];
#pragma unroll
        for (int nt = 0; nt < 4; nt++) {
            bf16x8 bq = *(const bf16x8*)&Qs[nt * 16 + fr][quad * 8];
#pragma unroll
            for (int mt = 0; mt < 2; mt++) {
                f32x4 z = {0.f, 0.f, 0.f, 0.f};
                st[mt][nt] = __builtin_amdgcn_mfma_f32_16x16x32_bf16(af[mt], bq, z, 0, 0, 0);
            }
        }

        float pmax[4] = {-1e30f, -1e30f, -1e30f, -1e30f};
#pragma unroll
        for (int nt = 0; nt < 4; nt++) {
            unsigned mword = Mq[nt * 16 + fr][w];
#pragma unroll
            for (int mt = 0; mt < 2; mt++)
#pragma unroll
                for (int r = 0; r < 4; r++) {
                    int bitpos = mt * 16 + quad * 4 + r;
                    float v = st[mt][nt][r];
                    if (!((mword >> bitpos) & 1u)) v -= 10000.f;
                    st[mt][nt][r] = v;
                    pmax[nt] = fmaxf(pmax[nt], v);
                }
        }
#pragma unroll
        for (int nt = 0; nt < 4; nt++)
            red[nt * 16 + fr][w * 4 + quad] = pmax[nt];
        __syncthreads();

        if (t < QT) {
            float mt_ = -1e30f;
#pragma unroll
            for (int k = 0; k < 16; k++) mt_ = fmaxf(mt_, red[t][k]);
            float mo = m_s[t], mn = fmaxf(mo, mt_);
            m_s[t] = mn;
            alpha_s[t] = __expf(mo - mn);
        }
        __syncthreads();

        float psum[4] = {0.f, 0.f, 0.f, 0.f};
#pragma unroll
        for (int nt = 0; nt < 4; nt++) {
            float mrow = m_s[nt * 16 + fr];
#pragma unroll
            for (int mt = 0; mt < 2; mt++) {
                float p0 = __expf(st[mt][nt][0] - mrow);
                float p1 = __expf(st[mt][nt][1] - mrow);
                float p2 = __expf(st[mt][nt][2] - mrow);
                float p3 = __expf(st[mt][nt][3] - mrow);
                psum[nt] += p0 + p1 + p2 + p3;
                uint2 pk;
                pk.x = pkbf(p0, p1);
                pk.y = pkbf(p2, p3);
                *(uint2*)&Ps[nt * 16 + fr][w * 32 + mt * 16 + quad * 4] = pk;
            }
        }
#pragma unroll
        for (int nt = 0; nt < 4; nt++)
            red[nt * 16 + fr][w * 4 + quad] = psum[nt];
        __syncthreads();

        if (t < QT) {
            float s = 0.f;
#pragma unroll
            for (int k = 0; k < 16; k++) s += red[t][k];
            l_s[t] = l_s[t] * alpha_s[t] + s;
        }

#pragma unroll
        for (int r = 0; r < 4; r++) {
            float a = alpha_s[w * 16 + quad * 4 + r];
            oacc[0][r] *= a; oacc[1][r] *= a;
        }
#pragma unroll
        for (int k0 = 0; k0 < ST; k0 += 32) {
            bf16x8 ap = *(const bf16x8*)&Ps[w * 16 + fr][k0 + quad * 8];
            bf16x8 bv0 = *(const bf16x8*)&Vt[fr][k0 + quad * 8];
            bf16x8 bv1 = *(const bf16x8*)&Vt[16 + fr][k0 + quad * 8];
            oacc[0] = __builtin_amdgcn_mfma_f32_16x16x32_bf16(ap, bv0, oacc[0], 0, 0, 0);
            oacc[1] = __builtin_amdgcn_mfma_f32_16x16x32_bf16(ap, bv1, oacc[1], 0, 0, 0);
        }
    }
    __syncthreads();

    int part = b * NSPLIT + sp;
    if (t < qlim) {
        mpart[((size_t)part * HH + h) * BQ + q0 + t] = m_s[t];
        lpart[((size_t)part * HH + h) * BQ + q0 + t] = l_s[t];
    }
#pragma unroll
    for (int nd = 0; nd < 2; nd++) {
#pragma unroll
        for (int r = 0; r < 4; r++) {
            int q = w * 16 + quad * 4 + r;
            if (q < qlim)
                Opart[((size_t)part * BQ + q0 + q) * DD + h * HDD + nd * 16 + fr] = oacc[nd][r];
        }
    }
}

// ---------------- self-attention (S=Q=100) ----------------------------------
__global__ void attn_kernel(const float* __restrict__ Qm, int sq, int qo0,
                            const float* __restrict__ Km, int sk, int ko0,
                            const float* __restrict__ Vm, int sv, int vo0,
                            float* __restrict__ Out, int so, int oo0,
                            int Slen, int Qlen, float scale) {
    int q = blockIdx.x, h = blockIdx.y, b = blockIdx.z;
    int tid = threadIdx.x;
    __shared__ float qv[32];
    __shared__ float sc[128];
    __shared__ float red[256];
    __shared__ float part[8][33];
    int qrow = b * Qlen + q;
    if (tid < 32) qv[tid] = Qm[(size_t)qrow * sq + qo0 + h * HDD + tid] * scale;
    __syncthreads();

    float lmax = -1e30f;
    for (int s = tid; s < Slen; s += 256) {
        const float* kp = Km + (size_t)(b * Slen + s) * sk + ko0 + h * HDD;
        float dot = 0.f;
#pragma unroll
        for (int d = 0; d < HDD; d += 4) {
            float4 k4 = *(const float4*)(kp + d);
            dot += qv[d] * k4.x + qv[d + 1] * k4.y + qv[d + 2] * k4.z + qv[d + 3] * k4.w;
        }
        sc[s] = dot;
        lmax = fmaxf(lmax, dot);
    }
    red[tid] = lmax; __syncthreads();
    for (int off = 128; off > 0; off >>= 1) {
        if (tid < off) red[tid] = fmaxf(red[tid], red[tid + off]);
        __syncthreads();
    }
    float m = red[0];
    __syncthreads();
    float lsum = 0.f;
    for (int s = tid; s < Slen; s += 256) {
        float e = __expf(sc[s] - m);
        sc[s] = e;
        lsum += e;
    }
    red[tid] = lsum; __syncthreads();
    for (int off = 128; off > 0; off >>= 1) {
        if (tid < off) red[tid] += red[tid + off];
        __syncthreads();
    }
    float inv = 1.0f / red[0];

    int d = tid & 31, g = tid >> 5;
    float acc = 0.f;
    for (int s = g; s < Slen; s += 8)
        acc += sc[s] * Vm[(size_t)(b * Slen + s) * sv + vo0 + h * HDD + d];
    part[g][d] = acc; __syncthreads();
    if (g == 0) {
        float t = 0.f;
#pragma unroll
        for (int gg = 0; gg < 8; gg++) t += part[gg][d];
        Out[(size_t)qrow * so + oo0 + h * HDD + d] = t * inv;
    }
}

extern "C" void kernel_launch(void* const* d_in, const int* in_sizes, int n_in,
                              void* d_out, int out_size, void* d_ws, size_t ws_size,
                              hipStream_t stream) {
    const float* queries    = (const float*)d_in[0];
    const float* pixel_feat = (const float*)d_in[1];
    const float* prev_mask  = (const float*)d_in[2];
    const float* cross_in_w  = (const float*)d_in[3];
    const float* cross_in_b  = (const float*)d_in[4];
    const float* cross_out_w = (const float*)d_in[5];
    const float* cross_out_b = (const float*)d_in[6];
    const float* self_in_w   = (const float*)d_in[7];
    const float* self_in_b   = (const float*)d_in[8];
    const float* self_out_w  = (const float*)d_in[9];
    const float* self_out_b  = (const float*)d_in[10];
    const float* ln_cross_g  = (const float*)d_in[11];
    const float* ln_cross_b  = (const float*)d_in[12];
    const float* ln_self_g   = (const float*)d_in[13];
    const float* ln_self_b   = (const float*)d_in[14];
    const float* ln_ffn_g    = (const float*)d_in[15];
    const float* ln_ffn_b    = (const float*)d_in[16];
    const float* ffn_w1 = (const float*)d_in[17];
    const float* ffn_b1 = (const float*)d_in[18];
    const float* ffn_w2 = (const float*)d_in[19];
    const float* ffn_b2 = (const float*)d_in[20];
    float* out = (float*)d_out;

    const int NQ = SB * BQ;        // 800
    const int NK = SB * SS;        // 32768

    float* ws = (float*)d_ws;
    unsigned* Mbits = (unsigned*)ws;   ws += (size_t)NQ * 128;
    float* q_cross  = ws;              ws += (size_t)NQ * DD;
    unsigned short* Kbk = (unsigned short*)ws;
    ws += (size_t)NK * DD / 2;
    unsigned short* Vbk = (unsigned short*)ws;
    ws += (size_t)NK * DD / 2;
    float* queries1 = ws;              ws += (size_t)NQ * DD;
    float* qkv      = ws;              ws += (size_t)NQ * 3 * DD;
    float* attn2    = ws;              ws += (size_t)NQ * DD;
    float* queries2 = ws;              ws += (size_t)NQ * DD;
    float* ffn_h    = ws;              ws += (size_t)NQ * 4 * DD;
    float* Csplit   = ws;              ws += (size_t)4 * MROWS * DD;
    float* Opart    = ws;              ws += (size_t)SB * NSPLIT * BQ * DD;
    float* mpart    = ws;              ws += (size_t)SB * NSPLIT * HH * BQ;
    float* lpart    = ws;              ws += (size_t)SB * NSPLIT * HH * BQ;

    const float scale = 0.17677669529663687f;

    // ---- stage1: KV proj + maskpack + LN/Q-proj (one dispatch) ----
    stage1<<<1874, 256, 0, stream>>>(
        queries, ln_cross_g, ln_cross_b, cross_in_w, cross_in_b, q_cross,
        pixel_feat, Kbk, Vbk, prev_mask, Mbits);

    // ---- cross attention ----
    cross_attn_mfma<<<dim3(2, HH, SB * NSPLIT), 256, 0, stream>>>(
        q_cross, Kbk, Vbk, Mbits, Opart, mpart, lpart);
    comb_gemm<<<dim3(8, 25), 64, 0, stream>>>(
        Opart, mpart, lpart, cross_out_w, cross_out_b, queries, queries1);

    // ---- self attention ----
    ln_gemm<0><<<dim3(24, 25), 64, 0, stream>>>(
        queries1, ln_self_g, ln_self_b, self_in_w, self_in_b, nullptr,
        qkv, 3 * DD);
    attn_kernel<<<dim3(BQ, HH, SB), 256, 0, stream>>>(
        qkv, 3 * DD, 0, qkv, 3 * DD, DD, qkv, 3 * DD, 2 * DD,
        attn2, DD, 0, BQ, BQ, scale);
    gemm_skinny2<256, 1, 2><<<dim3(8, 25), 64, 0, stream>>>(
        attn2, self_out_w, self_out_b, queries1, queries2, nullptr, DD);

    // ---- FFN ----
    ln_gemm<1><<<dim3(32, 25), 64, 0, stream>>>(
        queries2, ln_ffn_g, ln_ffn_b, ffn_w1, ffn_b1, nullptr,
        ffn_h, 4 * DD);
    gemm_skinny2<1024, 4, 2><<<dim3(8, 25, 4), 64, 0, stream>>>(
        ffn_h, ffn_w2, ffn_b2, nullptr, nullptr, Csplit, DD);
    gemm_combine<4, 2><<<MROWS, 256, 0, stream>>>(
        Csplit, ffn_b2, queries2, out, DD);
}

// Round 13
// 255.500 us; speedup vs baseline: 1.2339x; 1.0186x over previous
//
#include <hip/hip_runtime.h>
#include <hip/hip_bf16.h>
#include <math.h>

#define BQ 100
#define SB 8
#define SS 4096
#define DD 256
#define HH 8
#define HDD 32
#define NSPLIT 4
#define SCHUNK (SS / NSPLIT)   // 1024
#define MROWS 800              // SB*BQ

typedef __attribute__((ext_vector_type(8))) short bf16x8;
typedef __attribute__((ext_vector_type(4))) float f32x4;

__device__ inline unsigned short f2bf(float f) {
    union { float f; unsigned u; } v; v.f = f;
    unsigned r = v.u + 0x7fff + ((v.u >> 16) & 1);
    return (unsigned short)(r >> 16);
}

// HW packed fp32x2 -> bf16x2 (v_cvt_pk_bf16_f32 on gfx950), RNE
__device__ inline unsigned pkbf(float x, float y) {
    union { __hip_bfloat162 h; unsigned u; } c;
    c.h = __float22bfloat162_rn(make_float2(x, y));
    return c.u;
}

__device__ inline bf16x8 load_bf8(const float* p) {
    float4 a = *(const float4*)p;
    float4 b = *(const float4*)(p + 4);
    union { unsigned u[4]; bf16x8 v; } r;
    r.u[0] = pkbf(a.x, a.y); r.u[1] = pkbf(a.z, a.w);
    r.u[2] = pkbf(b.x, b.y); r.u[3] = pkbf(b.z, b.w);
    return r.v;
}

#define TM 128
#define TN 128
#define TK 32
#define LSTR 40

// ============ stage1: fused {KV projection | maskpack | LN+Q-projection} ====
// grid.x: [0,1024) KV proj tiles (XCD-swizzled); [1024,1824) maskpack rows;
// [1824,1874) LN+Qproj.
__global__ __launch_bounds__(256, 4) void stage1(
        const float* __restrict__ queries,
        const float* __restrict__ ln_g, const float* __restrict__ ln_b,
        const float* __restrict__ cw, const float* __restrict__ cb,
        float* __restrict__ q_cross,
        const float* __restrict__ pixel_feat,
        unsigned short* __restrict__ Kb, unsigned short* __restrict__ Vb,
        const float* __restrict__ mask, unsigned* __restrict__ Mbits) {
    __shared__ __align__(16) char smem[21504];
    const int bid = blockIdx.x;
    const int t = threadIdx.x;

    if (bid < 1024) {
        typedef unsigned short (*tile_t)[LSTR];
        tile_t As = (tile_t)smem;
        tile_t Bs = (tile_t)(smem + 128 * LSTR * 2);
        const float* A = pixel_feat;
        const float* W = cw + (size_t)DD * DD;
        const float* bias = cb + DD;
        // XCD-aware swizzle: the 4 n-tiles sharing an A-tile land on one XCD
        // (dispatch round-robins blockIdx.x % 8 across XCDs), so the A-tile is
        // fetched into that XCD's L2 once and hit 3x.
        int xcd = bid & 7, idx = bid >> 3;         // idx 0..127
        int mt = xcd + 8 * (idx >> 2);             // 0..255
        int nt = idx & 3;                          // 0..3
        int m0 = mt * TM, n0 = nt * TN;
        int wave = t / 64, lane = t % 64;
        int wm = (wave % 2) * 64, wn = (wave / 2) * 64;
        int lr = t / 4, lc = (t % 4) * 8;
        int fr = lane % 16, quad = lane / 16;
        f32x4 acc[4][4] = {};
        for (int k0 = 0; k0 < DD; k0 += TK) {
            __syncthreads();
#pragma unroll
            for (int half = 0; half < 2; half++) {
                int r = lr + half * 64;
                float4 a0 = *(const float4*)(A + (size_t)(m0 + r) * DD + k0 + lc);
                float4 a1 = *(const float4*)(A + (size_t)(m0 + r) * DD + k0 + lc + 4);
                uint4 pa;
                pa.x = pkbf(a0.x, a0.y); pa.y = pkbf(a0.z, a0.w);
                pa.z = pkbf(a1.x, a1.y); pa.w = pkbf(a1.z, a1.w);
                *(uint4*)&As[r][lc] = pa;
                float4 b0 = *(const float4*)(W + (size_t)(n0 + r) * DD + k0 + lc);
                float4 b1 = *(const float4*)(W + (size_t)(n0 + r) * DD + k0 + lc + 4);
                uint4 pb;
                pb.x = pkbf(b0.x, b0.y); pb.y = pkbf(b0.z, b0.w);
                pb.z = pkbf(b1.x, b1.y); pb.w = pkbf(b1.z, b1.w);
                *(uint4*)&Bs[r][lc] = pb;
            }
            __syncthreads();
            bf16x8 af[4], bf[4];
#pragma unroll
            for (int mi = 0; mi < 4; mi++)
                af[mi] = *(const bf16x8*)&As[wm + mi * 16 + fr][quad * 8];
#pragma unroll
            for (int ni = 0; ni < 4; ni++)
                bf[ni] = *(const bf16x8*)&Bs[wn + ni * 16 + fr][quad * 8];
#pragma unroll
            for (int mi = 0; mi < 4; mi++)
#pragma unroll
                for (int ni = 0; ni < 4; ni++)
                    acc[mi][ni] = __builtin_amdgcn_mfma_f32_16x16x32_bf16(
                        af[mi], bf[ni], acc[mi][ni], 0, 0, 0);
        }
#pragma unroll
        for (int ni = 0; ni < 4; ni++) {
            int n = n0 + wn + ni * 16 + fr;
            float bv = bias[n];
            unsigned short* dst = (n < 256) ? Kb : Vb;
            int hh = (n >> 5) & 7, d = n & 31;
#pragma unroll
            for (int mi = 0; mi < 4; mi++) {
#pragma unroll
                for (int r = 0; r < 4; r++) {
                    int m = m0 + wm + mi * 16 + quad * 4 + r;
                    int bb = m >> 12, s = m & (SS - 1);
                    dst[((((size_t)bb * HH + hh) * SS + s) << 5) + d] =
                        f2bf(acc[mi][ni][r] + bv);
                }
            }
        }
    } else if (bid < 1824) {
        int row = bid - 1024;
        unsigned* words = (unsigned*)smem;
        unsigned* orred = (unsigned*)(smem + 512);
        int w = t >> 6, lane = t & 63;
        unsigned lor = 0;
        for (int i = 0; i < 16; i++) {
            int s = (w * 16 + i) * 64 + lane;
            unsigned long long bal = __ballot(mask[(size_t)row * SS + s] > 0.f);
            if (lane == 0) {
                words[(w * 16 + i) * 2] = (unsigned)bal;
                words[(w * 16 + i) * 2 + 1] = (unsigned)(bal >> 32);
            }
            lor |= (unsigned)(bal | (bal >> 32));
        }
        if (lane == 0) orred[w] = lor;
        __syncthreads();
        unsigned anyv = orred[0] | orred[1] | orred[2] | orred[3];
        if (t < 128) Mbits[(size_t)row * 128 + t] = anyv ? words[t] : 0xFFFFFFFFu;
    } else {
        typedef unsigned short (*arow_t)[264];
        arow_t Aq = (arow_t)smem;
        float* mu_s = (float*)(smem + 16896);
        float* rs_s = mu_s + 32;
        float (*prt)[8][2] = (float(*)[8][2])(rs_s + 32);
        int idx = bid - 1824;
        int nq = idx & 1, my = idx >> 1;
        int m0 = my * 32;
        int row = t & 31, cs = t >> 5;
        const float* xp = queries + (size_t)(m0 + row) * DD + cs * 32;
        float s = 0.f, ss = 0.f;
#pragma unroll
        for (int c = 0; c < 32; c += 4) {
            float4 v = *(const float4*)(xp + c);
            s += v.x + v.y + v.z + v.w;
            ss += v.x * v.x + v.y * v.y + v.z * v.z + v.w * v.w;
        }
        prt[row][cs][0] = s; prt[row][cs][1] = ss;
        __syncthreads();
        if (t < 32) {
            float sum = 0.f, sq = 0.f;
#pragma unroll
            for (int k = 0; k < 8; k++) { sum += prt[t][k][0]; sq += prt[t][k][1]; }
            float mu = sum * (1.0f / DD);
            float var = sq * (1.0f / DD) - mu * mu;
            mu_s[t] = mu;
            rs_s[t] = rsqrtf(var + 1e-5f);
        }
        __syncthreads();
        {
            float mu = mu_s[row], r = rs_s[row];
            int col0 = cs * 32;
#pragma unroll
            for (int c = 0; c < 32; c += 8) {
                int col = col0 + c;
                float4 v0 = *(const float4*)(xp + c);
                float4 v1 = *(const float4*)(xp + c + 4);
                float4 g0 = *(const float4*)(ln_g + col);
                float4 g1 = *(const float4*)(ln_g + col + 4);
                float4 b0 = *(const float4*)(ln_b + col);
                float4 b1 = *(const float4*)(ln_b + col + 4);
                uint4 pk;
                pk.x = pkbf((v0.x - mu) * r * g0.x + b0.x, (v0.y - mu) * r * g0.y + b0.y);
                pk.y = pkbf((v0.z - mu) * r * g0.z + b0.z, (v0.w - mu) * r * g0.w + b0.w);
                pk.z = pkbf((v1.x - mu) * r * g1.x + b1.x, (v1.y - mu) * r * g1.y + b1.y);
                pk.w = pkbf((v1.z - mu) * r * g1.z + b1.z, (v1.w - mu) * r * g1.w + b1.w);
                *(uint4*)&Aq[row][col] = pk;
            }
        }
        __syncthreads();
        int w = t >> 6, lane = t & 63;
        int fr = lane & 15, quad = lane >> 4;
        int n0 = nq * 128 + w * 32;
        f32x4 acc[2][2] = {};
        const float* Wp0 = cw + (size_t)(n0 + fr) * DD + quad * 8;
        const float* Wp1 = Wp0 + (size_t)16 * DD;
#pragma unroll
        for (int k0 = 0; k0 < DD; k0 += 32) {
            bf16x8 a0 = *(const bf16x8*)&Aq[fr][k0 + quad * 8];
            bf16x8 a1 = *(const bf16x8*)&Aq[16 + fr][k0 + quad * 8];
            bf16x8 w0 = load_bf8(Wp0 + k0);
            bf16x8 w1 = load_bf8(Wp1 + k0);
            acc[0][0] = __builtin_amdgcn_mfma_f32_16x16x32_bf16(a0, w0, acc[0][0], 0, 0, 0);
            acc[0][1] = __builtin_amdgcn_mfma_f32_16x16x32_bf16(a0, w1, acc[0][1], 0, 0, 0);
            acc[1][0] = __builtin_amdgcn_mfma_f32_16x16x32_bf16(a1, w0, acc[1][0], 0, 0, 0);
            acc[1][1] = __builtin_amdgcn_mfma_f32_16x16x32_bf16(a1, w1, acc[1][1], 0, 0, 0);
        }
#pragma unroll
        for (int ni = 0; ni < 2; ni++) {
            int n = n0 + ni * 16 + fr;
            float bv = cb[n];
#pragma unroll
            for (int mi = 0; mi < 2; mi++) {
#pragma unroll
                for (int r = 0; r < 4; r++) {
                    int m = m0 + mi * 16 + quad * 4 + r;
                    q_cross[(size_t)m * DD + n] = acc[mi][ni][r] + bv;
                }
            }
        }
    }
}

// ---------------- fused LayerNorm + one-wave MFMA GEMM ----------------------
template<int MODE>
__global__ __launch_bounds__(64, 4) void ln_gemm(
        const float* __restrict__ X, const float* __restrict__ gam,
        const float* __restrict__ bet,
        const float* __restrict__ W, const float* __restrict__ bias,
        const float* __restrict__ res,
        float* __restrict__ C, int N) {
    __shared__ unsigned short As[32][264];
    __shared__ float mu_s[32], rs_s[32];
    __shared__ float prt[32][2][2];
    const int t = threadIdx.x;
    const int fr = t & 15, quad = t >> 4;
    const int m0 = blockIdx.y * 32, n0 = blockIdx.x * 32;
    const int row = t & 31, half = t >> 5;

    const float* xp = X + (size_t)(m0 + row) * DD + half * 128;
    float s = 0.f, ss = 0.f;
#pragma unroll
    for (int c = 0; c < 128; c += 4) {
        float4 v = *(const float4*)(xp + c);
        s += v.x + v.y + v.z + v.w;
        ss += v.x * v.x + v.y * v.y + v.z * v.z + v.w * v.w;
    }
    prt[row][half][0] = s;
    prt[row][half][1] = ss;
    __syncthreads();
    if (t < 32) {
        float sum = prt[t][0][0] + prt[t][1][0];
        float sq  = prt[t][0][1] + prt[t][1][1];
        float mu = sum * (1.0f / DD);
        float var = sq * (1.0f / DD) - mu * mu;
        mu_s[t] = mu;
        rs_s[t] = rsqrtf(var + 1e-5f);
    }
    __syncthreads();
    {
        float mu = mu_s[row], r = rs_s[row];
#pragma unroll
        for (int c = 0; c < 128; c += 8) {
            int col = half * 128 + c;
            float4 v0 = *(const float4*)(xp + c);
            float4 v1 = *(const float4*)(xp + c + 4);
            float4 g0 = *(const float4*)(gam + col);
            float4 g1 = *(const float4*)(gam + col + 4);
            float4 b0 = *(const float4*)(bet + col);
            float4 b1 = *(const float4*)(bet + col + 4);
            uint4 pk;
            pk.x = pkbf((v0.x - mu) * r * g0.x + b0.x, (v0.y - mu) * r * g0.y + b0.y);
            pk.y = pkbf((v0.z - mu) * r * g0.z + b0.z, (v0.w - mu) * r * g0.w + b0.w);
            pk.z = pkbf((v1.x - mu) * r * g1.x + b1.x, (v1.y - mu) * r * g1.y + b1.y);
            pk.w = pkbf((v1.z - mu) * r * g1.z + b1.z, (v1.w - mu) * r * g1.w + b1.w);
            *(uint4*)&As[row][col] = pk;
        }
    }
    __syncthreads();

    f32x4 acc[2][2] = {};
    const float* Wp0 = W + (size_t)(n0 + fr) * DD + quad * 8;
    const float* Wp1 = Wp0 + (size_t)16 * DD;
#pragma unroll
    for (int k0 = 0; k0 < DD; k0 += 32) {
        bf16x8 a0 = *(const bf16x8*)&As[fr][k0 + quad * 8];
        bf16x8 a1 = *(const bf16x8*)&As[16 + fr][k0 + quad * 8];
        bf16x8 w0 = load_bf8(Wp0 + k0);
        bf16x8 w1 = load_bf8(Wp1 + k0);
        acc[0][0] = __builtin_amdgcn_mfma_f32_16x16x32_bf16(a0, w0, acc[0][0], 0, 0, 0);
        acc[0][1] = __builtin_amdgcn_mfma_f32_16x16x32_bf16(a0, w1, acc[0][1], 0, 0, 0);
        acc[1][0] = __builtin_amdgcn_mfma_f32_16x16x32_bf16(a1, w0, acc[1][0], 0, 0, 0);
        acc[1][1] = __builtin_amdgcn_mfma_f32_16x16x32_bf16(a1, w1, acc[1][1], 0, 0, 0);
    }

#pragma unroll
    for (int ni = 0; ni < 2; ni++) {
        int n = n0 + ni * 16 + fr;
        float bv = bias[n];
#pragma unroll
        for (int mi = 0; mi < 2; mi++) {
#pragma unroll
            for (int r = 0; r < 4; r++) {
                int m = m0 + mi * 16 + quad * 4 + r;
                float v = acc[mi][ni][r] + bv;
                if (MODE == 1) {
                    v = 0.5f * v * (1.0f + erff(v * 0.70710678118654752f));
                } else if (MODE == 2) {
                    v += res[(size_t)m * N + n];
                }
                C[(size_t)m * N + n] = v;
            }
        }
    }
}

// ---------------- fused split-S combine + output projection -----------------
__global__ __launch_bounds__(64, 4) void comb_gemm(
        const float* __restrict__ Opart, const float* __restrict__ mpart,
        const float* __restrict__ lpart,
        const float* __restrict__ W, const float* __restrict__ bias,
        const float* __restrict__ res,
        float* __restrict__ C) {
    __shared__ unsigned short As[32][264];
    const int t = threadIdx.x;
    const int fr = t & 15, quad = t >> 4;
    const int m0 = blockIdx.y * 32, n0 = blockIdx.x * 32;
    const int row = t & 31, half = t >> 5;

    {
        int m = m0 + row;
        int b = m / BQ, q = m % BQ;
#pragma unroll
        for (int h = half * 4; h < half * 4 + 4; h++) {
            float mv[NSPLIT], wsp[NSPLIT];
            float mstar = -1e30f;
#pragma unroll
            for (int sp = 0; sp < NSPLIT; sp++) {
                mv[sp] = mpart[((size_t)(b * NSPLIT + sp) * HH + h) * BQ + q];
                mstar = fmaxf(mstar, mv[sp]);
            }
            float lstar = 0.f;
#pragma unroll
            for (int sp = 0; sp < NSPLIT; sp++) {
                wsp[sp] = __expf(mv[sp] - mstar);
                lstar += lpart[((size_t)(b * NSPLIT + sp) * HH + h) * BQ + q] * wsp[sp];
            }
            float inv = 1.0f / lstar;
#pragma unroll
            for (int d = 0; d < HDD; d += 8) {
                float o[8] = {};
#pragma unroll
                for (int sp = 0; sp < NSPLIT; sp++) {
                    const float* op = Opart +
                        ((size_t)(b * NSPLIT + sp) * BQ + q) * DD + h * HDD + d;
                    float4 a = *(const float4*)op;
                    float4 b4 = *(const float4*)(op + 4);
                    o[0] += a.x * wsp[sp];  o[1] += a.y * wsp[sp];
                    o[2] += a.z * wsp[sp];  o[3] += a.w * wsp[sp];
                    o[4] += b4.x * wsp[sp]; o[5] += b4.y * wsp[sp];
                    o[6] += b4.z * wsp[sp]; o[7] += b4.w * wsp[sp];
                }
                uint4 pk;
                pk.x = pkbf(o[0] * inv, o[1] * inv);
                pk.y = pkbf(o[2] * inv, o[3] * inv);
                pk.z = pkbf(o[4] * inv, o[5] * inv);
                pk.w = pkbf(o[6] * inv, o[7] * inv);
                *(uint4*)&As[row][h * HDD + d] = pk;
            }
        }
    }
    __syncthreads();

    f32x4 acc[2][2] = {};
    const float* Wp0 = W + (size_t)(n0 + fr) * DD + quad * 8;
    const float* Wp1 = Wp0 + (size_t)16 * DD;
#pragma unroll
    for (int k0 = 0; k0 < DD; k0 += 32) {
        bf16x8 a0 = *(const bf16x8*)&As[fr][k0 + quad * 8];
        bf16x8 a1 = *(const bf16x8*)&As[16 + fr][k0 + quad * 8];
        bf16x8 w0 = load_bf8(Wp0 + k0);
        bf16x8 w1 = load_bf8(Wp1 + k0);
        acc[0][0] = __builtin_amdgcn_mfma_f32_16x16x32_bf16(a0, w0, acc[0][0], 0, 0, 0);
        acc[0][1] = __builtin_amdgcn_mfma_f32_16x16x32_bf16(a0, w1, acc[0][1], 0, 0, 0);
        acc[1][0] = __builtin_amdgcn_mfma_f32_16x16x32_bf16(a1, w0, acc[1][0], 0, 0, 0);
        acc[1][1] = __builtin_amdgcn_mfma_f32_16x16x32_bf16(a1, w1, acc[1][1], 0, 0, 0);
    }

#pragma unroll
    for (int ni = 0; ni < 2; ni++) {
        int n = n0 + ni * 16 + fr;
        float bv = bias[n];
#pragma unroll
        for (int mi = 0; mi < 2; mi++) {
#pragma unroll
            for (int r = 0; r < 4; r++) {
                int m = m0 + mi * 16 + quad * 4 + r;
                float v = acc[mi][ni][r] + bv + res[(size_t)m * DD + n];
                C[(size_t)m * DD + n] = v;
            }
        }
    }
}

// ---------------- one-wave MFMA GEMM: 32x32 tile/block, optional split-K ----
template<int KK, int SPLITK, int MODE>
__global__ __launch_bounds__(64, 4) void gemm_skinny2(
        const float* __restrict__ A, const float* __restrict__ W,
        const float* __restrict__ bias, const float* __restrict__ res,
        float* __restrict__ C, float* __restrict__ Cp, int N) {
    const int lane = threadIdx.x;
    const int fr = lane & 15, quad = lane >> 4;
    const int m0 = blockIdx.y * 32;
    const int n0 = blockIdx.x * 32;
    const int sk = blockIdx.z;
    const int KCH = KK / SPLITK;

    f32x4 acc[2][2] = {};
    const float* Ap0 = A + (size_t)(m0 + fr) * KK + sk * KCH + quad * 8;
    const float* Ap1 = Ap0 + (size_t)16 * KK;
    const float* Wp0 = W + (size_t)(n0 + fr) * KK + sk * KCH + quad * 8;
    const float* Wp1 = Wp0 + (size_t)16 * KK;

#pragma unroll
    for (int k0 = 0; k0 < KCH; k0 += 32) {
        bf16x8 a0 = load_bf8(Ap0 + k0);
        bf16x8 a1 = load_bf8(Ap1 + k0);
        bf16x8 w0 = load_bf8(Wp0 + k0);
        bf16x8 w1 = load_bf8(Wp1 + k0);
        acc[0][0] = __builtin_amdgcn_mfma_f32_16x16x32_bf16(a0, w0, acc[0][0], 0, 0, 0);
        acc[0][1] = __builtin_amdgcn_mfma_f32_16x16x32_bf16(a0, w1, acc[0][1], 0, 0, 0);
        acc[1][0] = __builtin_amdgcn_mfma_f32_16x16x32_bf16(a1, w0, acc[1][0], 0, 0, 0);
        acc[1][1] = __builtin_amdgcn_mfma_f32_16x16x32_bf16(a1, w1, acc[1][1], 0, 0, 0);
    }

    if (SPLITK == 1) {
#pragma unroll
        for (int ni = 0; ni < 2; ni++) {
            int n = n0 + ni * 16 + fr;
            float bv = bias[n];
#pragma unroll
            for (int mi = 0; mi < 2; mi++) {
#pragma unroll
                for (int r = 0; r < 4; r++) {
                    int m = m0 + mi * 16 + quad * 4 + r;
                    float v = acc[mi][ni][r] + bv;
                    if (MODE == 1) {
                        v = 0.5f * v * (1.0f + erff(v * 0.70710678118654752f));
                    } else if (MODE == 2) {
                        v += res[(size_t)m * N + n];
                    }
                    C[(size_t)m * N + n] = v;
                }
            }
        }
    } else {
        float* dst = Cp + (size_t)sk * MROWS * N;
#pragma unroll
        for (int ni = 0; ni < 2; ni++) {
            int n = n0 + ni * 16 + fr;
#pragma unroll
            for (int mi = 0; mi < 2; mi++) {
#pragma unroll
                for (int r = 0; r < 4; r++) {
                    int m = m0 + mi * 16 + quad * 4 + r;
                    dst[(size_t)m * N + n] = acc[mi][ni][r];
                }
            }
        }
    }
}

// ---------------- split-K combine: sum partials + epilogue ------------------
template<int SPLITK, int MODE>
__global__ void gemm_combine(const float* __restrict__ Cp,
                             const float* __restrict__ bias,
                             const float* __restrict__ res,
                             float* __restrict__ C, int N) {
    int m = blockIdx.x;
    for (int n = threadIdx.x; n < N; n += 256) {
        float v = bias[n];
#pragma unroll
        for (int sk = 0; sk < SPLITK; sk++)
            v += Cp[((size_t)sk * MROWS + m) * N + n];
        if (MODE == 1) {
            v = 0.5f * v * (1.0f + erff(v * 0.70710678118654752f));
        } else if (MODE == 2) {
            v += res[(size_t)m * N + n];
        }
        C[(size_t)m * N + n] = v;
    }
}

// ---------------- MFMA flash cross-attention, split-S, 64-q tiles -----------
#define QT 64
#define ST 128

__global__ __launch_bounds__(256) void cross_attn_mfma(
        const float* __restrict__ Qm,
        const unsigned short* __restrict__ Kb,
        const unsigned short* __restrict__ Vb,
        const unsigned* __restrict__ Mbits,
        float* __restrict__ Opart,
        float* __restrict__ mpart,
        float* __restrict__ lpart) {
    __shared__ unsigned short Qs[QT][40];
    __shared__ unsigned short Ks[ST][40];
    __shared__ unsigned short Vt[HDD][136];
    __shared__ unsigned short Ps[QT][136];
    __shared__ unsigned Mq[QT][4];
    __shared__ float red[QT][17];
    __shared__ float m_s[QT], alpha_s[QT], l_s[QT];

    const int qb = blockIdx.x, h = blockIdx.y;
    const int b = blockIdx.z / NSPLIT, sp = blockIdx.z % NSPLIT;
    const int t = threadIdx.x;
    const int w = t >> 6, lane = t & 63;
    const int fr = lane & 15, quad = lane >> 4;
    const int q0 = qb * QT;
    const int qlim = min(BQ - q0, QT);

    {
        int q = t >> 2, c0 = (t & 3) * 8;
        float4 v0 = make_float4(0.f, 0.f, 0.f, 0.f), v1 = v0;
        if (q < qlim) {
            const float* qp = Qm + (size_t)(b * BQ + q0 + q) * DD + h * HDD + c0;
            v0 = *(const float4*)qp;
            v1 = *(const float4*)(qp + 4);
        }
        const float sc = 0.17677669529663687f;
        uint4 pq;
        pq.x = pkbf(v0.x * sc, v0.y * sc);
        pq.y = pkbf(v0.z * sc, v0.w * sc);
        pq.z = pkbf(v1.x * sc, v1.y * sc);
        pq.w = pkbf(v1.z * sc, v1.w * sc);
        *(uint4*)&Qs[q][c0] = pq;
        if (t < QT) { m_s[t] = -1e30f; l_s[t] = 0.f; }
    }

    f32x4 oacc[2] = {};
    const unsigned short* Kbase = Kb + (((size_t)(b * HH + h)) * SS << 5);
    const unsigned short* Vbase = Vb + (((size_t)(b * HH + h)) * SS << 5);

    for (int s0 = sp * SCHUNK; s0 < (sp + 1) * SCHUNK; s0 += ST) {
        __syncthreads();
        {
            int r = t >> 1, half = t & 1;
            const unsigned short* kp = Kbase + ((size_t)(s0 + r) << 5) + half * 16;
            *(uint4*)&Ks[r][half * 16] = *(const uint4*)kp;
            *(uint4*)&Ks[r][half * 16 + 8] = *(const uint4*)(kp + 8);
            const unsigned short* vp = Vbase + ((size_t)(s0 + r) << 5) + half * 16;
            union { uint4 u; unsigned short s[8]; } v0, v1;
            v0.u = *(const uint4*)vp;
            v1.u = *(const uint4*)(vp + 8);
#pragma unroll
            for (int j = 0; j < 8; j++) Vt[half * 16 + j][r] = v0.s[j];
#pragma unroll
            for (int j = 0; j < 8; j++) Vt[half * 16 + 8 + j][r] = v1.s[j];
        }
        {
            int q = t >> 2, wd = t & 3;
            unsigned mword = 0xFFFFFFFFu;
            if (q < qlim)
                mword = Mbits[(size_t)(b * BQ + q0 + q) * 128 + (s0 >> 5) + wd];
            Mq[q][wd] = mword;
        }
        __syncthreads();

        bf16x8 af[2];
#pragma unroll
        for (int mt = 0; mt < 2; mt++)
            af[mt] = *(const bf16x8*)&Ks[w * 32 + mt * 16 + fr][quad * 8];
        f32x4 st[2][4];
#pragma unroll
        for (int nt = 0; nt < 4; nt++) {
            bf16x8 bq = *(const bf16x8*)&Qs[nt * 16 + fr][quad * 8];
#pragma unroll
            for (int mt = 0; mt < 2; mt++) {
                f32x4 z = {0.f, 0.f, 0.f, 0.f};
                st[mt][nt] = __builtin_amdgcn_mfma_f32_16x16x32_bf16(af[mt], bq, z, 0, 0, 0);
            }
        }

        float pmax[4] = {-1e30f, -1e30f, -1e30f, -1e30f};
#pragma unroll
        for (int nt = 0; nt < 4; nt++) {
            unsigned mword = Mq[nt * 16 + fr][w];
#pragma unroll
            for (int mt = 0; mt < 2; mt++)
#pragma unroll
                for (int r = 0; r < 4; r++) {
                    int bitpos = mt * 16 + quad * 4 + r;
                    float v = st[mt][nt][r];
                    if (!((mword >> bitpos) & 1u)) v -= 10000.f;
                    st[mt][nt][r] = v;
                    pmax[nt] = fmaxf(pmax[nt], v);
                }
        }
#pragma unroll
        for (int nt = 0; nt < 4; nt++)
            red[nt * 16 + fr][w * 4 + quad] = pmax[nt];
        __syncthreads();

        if (t < QT) {
            float mt_ = -1e30f;
#pragma unroll
            for (int k = 0; k < 16; k++) mt_ = fmaxf(mt_, red[t][k]);
            float mo = m_s[t], mn = fmaxf(mo, mt_);
            m_s[t] = mn;
            alpha_s[t] = __expf(mo - mn);
        }
        __syncthreads();

        float psum[4] = {0.f, 0.f, 0.f, 0.f};
#pragma unroll
        for (int nt = 0; nt < 4; nt++) {
            float mrow = m_s[nt * 16 + fr];
#pragma unroll
            for (int mt = 0; mt < 2; mt++) {
                float p0 = __expf(st[mt][nt][0] - mrow);
                float p1 = __expf(st[mt][nt][1] - mrow);
                float p2 = __expf(st[mt][nt][2] - mrow);
                float p3 = __expf(st[mt][nt][3] - mrow);
                psum[nt] += p0 + p1 + p2 + p3;
                uint2 pk;
                pk.x = pkbf(p0, p1);
                pk.y = pkbf(p2, p3);
                *(uint2*)&Ps[nt * 16 + fr][w * 32 + mt * 16 + quad * 4] = pk;
            }
        }
#pragma unroll
        for (int nt = 0; nt < 4; nt++)
            red[nt * 16 + fr][w * 4 + quad] = psum[nt];
        __syncthreads();

        if (t < QT) {
            float s = 0.f;
#pragma unroll
            for (int k = 0; k < 16; k++) s += red[t][k];
            l_s[t] = l_s[t] * alpha_s[t] + s;
        }

#pragma unroll
        for (int r = 0; r < 4; r++) {
            float a = alpha_s[w * 16 + quad * 4 + r];
            oacc[0][r] *= a; oacc[1][r] *= a;
        }
#pragma unroll
        for (int k0 = 0; k0 < ST; k0 += 32) {
            bf16x8 ap = *(const bf16x8*)&Ps[w * 16 + fr][k0 + quad * 8];
            bf16x8 bv0 = *(const bf16x8*)&Vt[fr][k0 + quad * 8];
            bf16x8 bv1 = *(const bf16x8*)&Vt[16 + fr][k0 + quad * 8];
            oacc[0] = __builtin_amdgcn_mfma_f32_16x16x32_bf16(ap, bv0, oacc[0], 0, 0, 0);
            oacc[1] = __builtin_amdgcn_mfma_f32_16x16x32_bf16(ap, bv1, oacc[1], 0, 0, 0);
        }
    }
    __syncthreads();

    int part = b * NSPLIT + sp;
    if (t < qlim) {
        mpart[((size_t)part * HH + h) * BQ + q0 + t] = m_s[t];
        lpart[((size_t)part * HH + h) * BQ + q0 + t] = l_s[t];
    }
#pragma unroll
    for (int nd = 0; nd < 2; nd++) {
#pragma unroll
        for (int r = 0; r < 4; r++) {
            int q = w * 16 + quad * 4 + r;
            if (q < qlim)
                Opart[((size_t)part * BQ + q0 + q) * DD + h * HDD + nd * 16 + fr] = oacc[nd][r];
        }
    }
}

// ---------------- self-attention (S=Q=100) ----------------------------------
__global__ void attn_kernel(const float* __restrict__ Qm, int sq, int qo0,
                            const float* __restrict__ Km, int sk, int ko0,
                            const float* __restrict__ Vm, int sv, int vo0,
                            float* __restrict__ Out, int so, int oo0,
                            int Slen, int Qlen, float scale) {
    int q = blockIdx.x, h = blockIdx.y, b = blockIdx.z;
    int tid = threadIdx.x;
    __shared__ float qv[32];
    __shared__ float sc[128];
    __shared__ float red[256];
    __shared__ float part[8][33];
    int qrow = b * Qlen + q;
    if (tid < 32) qv[tid] = Qm[(size_t)qrow * sq + qo0 + h * HDD + tid] * scale;
    __syncthreads();

    float lmax = -1e30f;
    for (int s = tid; s < Slen; s += 256) {
        const float* kp = Km + (size_t)(b * Slen + s) * sk + ko0 + h * HDD;
        float dot = 0.f;
#pragma unroll
        for (int d = 0; d < HDD; d += 4) {
            float4 k4 = *(const float4*)(kp + d);
            dot += qv[d] * k4.x + qv[d + 1] * k4.y + qv[d + 2] * k4.z + qv[d + 3] * k4.w;
        }
        sc[s] = dot;
        lmax = fmaxf(lmax, dot);
    }
    red[tid] = lmax; __syncthreads();
    for (int off = 128; off > 0; off >>= 1) {
        if (tid < off) red[tid] = fmaxf(red[tid], red[tid + off]);
        __syncthreads();
    }
    float m = red[0];
    __syncthreads();
    float lsum = 0.f;
    for (int s = tid; s < Slen; s += 256) {
        float e = __expf(sc[s] - m);
        sc[s] = e;
        lsum += e;
    }
    red[tid] = lsum; __syncthreads();
    for (int off = 128; off > 0; off >>= 1) {
        if (tid < off) red[tid] += red[tid + off];
        __syncthreads();
    }
    float inv = 1.0f / red[0];

    int d = tid & 31, g = tid >> 5;
    float acc = 0.f;
    for (int s = g; s < Slen; s += 8)
        acc += sc[s] * Vm[(size_t)(b * Slen + s) * sv + vo0 + h * HDD + d];
    part[g][d] = acc; __syncthreads();
    if (g == 0) {
        float t = 0.f;
#pragma unroll
        for (int gg = 0; gg < 8; gg++) t += part[gg][d];
        Out[(size_t)qrow * so + oo0 + h * HDD + d] = t * inv;
    }
}

extern "C" void kernel_launch(void* const* d_in, const int* in_sizes, int n_in,
                              void* d_out, int out_size, void* d_ws, size_t ws_size,
                              hipStream_t stream) {
    const float* queries    = (const float*)d_in[0];
    const float* pixel_feat = (const float*)d_in[1];
    const float* prev_mask  = (const float*)d_in[2];
    const float* cross_in_w  = (const float*)d_in[3];
    const float* cross_in_b  = (const float*)d_in[4];
    const float* cross_out_w = (const float*)d_in[5];
    const float* cross_out_b = (const float*)d_in[6];
    const float* self_in_w   = (const float*)d_in[7];
    const float* self_in_b   = (const float*)d_in[8];
    const float* self_out_w  = (const float*)d_in[9];
    const float* self_out_b  = (const float*)d_in[10];
    const float* ln_cross_g  = (const float*)d_in[11];
    const float* ln_cross_b  = (const float*)d_in[12];
    const float* ln_self_g   = (const float*)d_in[13];
    const float* ln_self_b   = (const float*)d_in[14];
    const float* ln_ffn_g    = (const float*)d_in[15];
    const float* ln_ffn_b    = (const float*)d_in[16];
    const float* ffn_w1 = (const float*)d_in[17];
    const float* ffn_b1 = (const float*)d_in[18];
    const float* ffn_w2 = (const float*)d_in[19];
    const float* ffn_b2 = (const float*)d_in[20];
    float* out = (float*)d_out;

    const int NQ = SB * BQ;        // 800
    const int NK = SB * SS;        // 32768

    float* ws = (float*)d_ws;
    unsigned* Mbits = (unsigned*)ws;   ws += (size_t)NQ * 128;
    float* q_cross  = ws;              ws += (size_t)NQ * DD;
    unsigned short* Kbk = (unsigned short*)ws;
    ws += (size_t)NK * DD / 2;
    unsigned short* Vbk = (unsigned short*)ws;
    ws += (size_t)NK * DD / 2;
    float* queries1 = ws;              ws += (size_t)NQ * DD;
    float* qkv      = ws;              ws += (size_t)NQ * 3 * DD;
    float* attn2    = ws;              ws += (size_t)NQ * DD;
    float* queries2 = ws;              ws += (size_t)NQ * DD;
    float* ffn_h    = ws;              ws += (size_t)NQ * 4 * DD;
    float* Csplit   = ws;              ws += (size_t)4 * MROWS * DD;
    float* Opart    = ws;              ws += (size_t)SB * NSPLIT * BQ * DD;
    float* mpart    = ws;              ws += (size_t)SB * NSPLIT * HH * BQ;
    float* lpart    = ws;              ws += (size_t)SB * NSPLIT * HH * BQ;

    const float scale = 0.17677669529663687f;

    // ---- stage1: KV proj + maskpack + LN/Q-proj (one dispatch) ----
    stage1<<<1874, 256, 0, stream>>>(
        queries, ln_cross_g, ln_cross_b, cross_in_w, cross_in_b, q_cross,
        pixel_feat, Kbk, Vbk, prev_mask, Mbits);

    // ---- cross attention ----
    cross_attn_mfma<<<dim3(2, HH, SB * NSPLIT), 256, 0, stream>>>(
        q_cross, Kbk, Vbk, Mbits, Opart, mpart, lpart);
    comb_gemm<<<dim3(8, 25), 64, 0, stream>>>(
        Opart, mpart, lpart, cross_out_w, cross_out_b, queries, queries1);

    // ---- self attention ----
    ln_gemm<0><<<dim3(24, 25), 64, 0, stream>>>(
        queries1, ln_self_g, ln_self_b, self_in_w, self_in_b, nullptr,
        qkv, 3 * DD);
    attn_kernel<<<dim3(BQ, HH, SB), 256, 0, stream>>>(
        qkv, 3 * DD, 0, qkv, 3 * DD, DD, qkv, 3 * DD, 2 * DD,
        attn2, DD, 0, BQ, BQ, scale);
    gemm_skinny2<256, 1, 2><<<dim3(8, 25), 64, 0, stream>>>(
        attn2, self_out_w, self_out_b, queries1, queries2, nullptr, DD);

    // ---- FFN ----
    ln_gemm<1><<<dim3(32, 25), 64, 0, stream>>>(
        queries2, ln_ffn_g, ln_ffn_b, ffn_w1, ffn_b1, nullptr,
        ffn_h, 4 * DD);
    gemm_skinny2<1024, 4, 2><<<dim3(8, 25, 4), 64, 0, stream>>>(
        ffn_h, ffn_w2, ffn_b2, nullptr, nullptr, Csplit, DD);
    gemm_combine<4, 2><<<MROWS, 256, 0, stream>>>(
        Csplit, ffn_b2, queries2, out, DD);
}